// Round 20
// baseline (291.052 us; speedup 1.0000x reference)
//
#include <hip/hip_runtime.h>
#include <hip/hip_bf16.h>
#include <math.h>

#define RR 32
#define R3 32768
#define BB 4
#define CI 64
#define CO 64
#define NN 4096

typedef short v8s __attribute__((ext_vector_type(8)));
typedef float v4f __attribute__((ext_vector_type(4)));
typedef unsigned short ushort_t;

__device__ __forceinline__ unsigned short f2bf(float f) {
    unsigned int u = __float_as_uint(f);
    unsigned int r = (u + 0x7FFFu + ((u >> 16) & 1u)) >> 16;
    return (unsigned short)r;
}
__device__ __forceinline__ float bf2f(unsigned short h) {
    return __uint_as_float((unsigned int)h << 16);
}

__device__ __forceinline__ void gll16(const void* g, void* l) {
    __builtin_amdgcn_global_load_lds((const __attribute__((address_space(1))) unsigned int*)g,
                                     (__attribute__((address_space(3))) unsigned int*)l, 16, 0, 0);
}

// ---------------- block reduce helpers ----------------
__device__ __forceinline__ float blockReduceSum(float v, float* sm) {
    int tid = threadIdx.x;
    sm[tid] = v; __syncthreads();
    for (int off = 128; off > 0; off >>= 1) {
        if (tid < off) sm[tid] += sm[tid + off];
        __syncthreads();
    }
    float r = sm[0]; __syncthreads();
    return r;
}
__device__ __forceinline__ float blockReduceMax(float v, float* sm) {
    int tid = threadIdx.x;
    sm[tid] = v; __syncthreads();
    for (int off = 128; off > 0; off >>= 1) {
        if (tid < off) sm[tid] = fmaxf(sm[tid], sm[tid + off]);
        __syncthreads();
    }
    float r = sm[0]; __syncthreads();
    return r;
}

// ---------------- voxel coords + fused voxel count ----------------
__global__ void k_nc(const float* __restrict__ coords, float* __restrict__ nc,
                     int* __restrict__ vidx, int* __restrict__ cntI) {
    int b = blockIdx.x, tid = threadIdx.x;
    __shared__ float sm[256];
    const float* cb = coords + (size_t)b * 3 * NN;
    float s0 = 0, s1 = 0, s2 = 0;
    for (int n = tid; n < NN; n += 256) {
        s0 += cb[n]; s1 += cb[NN + n]; s2 += cb[2 * NN + n];
    }
    float m0 = blockReduceSum(s0, sm) * (1.0f / NN);
    float m1 = blockReduceSum(s1, sm) * (1.0f / NN);
    float m2 = blockReduceSum(s2, sm) * (1.0f / NN);
    float mx = 0;
    for (int n = tid; n < NN; n += 256) {
        float dx = cb[n] - m0, dy = cb[NN + n] - m1, dz = cb[2 * NN + n] - m2;
        mx = fmaxf(mx, dx * dx + dy * dy + dz * dz);
    }
    mx = blockReduceMax(mx, sm);
    float denom = 2.0f * sqrtf(mx);
    float mean[3] = {m0, m1, m2};
    for (int n = tid; n < NN; n += 256) {
        int vi[3];
        #pragma unroll
        for (int ax = 0; ax < 3; ax++) {
            float x = (cb[ax * NN + n] - mean[ax]) / denom + 0.5f;
            x = x * RR;
            x = fminf(fmaxf(x, 0.0f), (float)(RR - 1));
            nc[((size_t)b * 3 + ax) * NN + n] = x;
            vi[ax] = (int)rintf(x);
        }
        int idx = (vi[0] * RR + vi[1]) * RR + vi[2];
        vidx[b * NN + n] = idx;
        atomicAdd(&cntI[b * R3 + idx], 1);
    }
}

// ---------------- scan ----------------
__global__ void k_scan1(const int* __restrict__ cntI, int* __restrict__ lscan,
                        int* __restrict__ bsum) {
    __shared__ int sm[256];
    int tid = threadIdx.x;
    int i = blockIdx.x * 256 + tid;
    int v = cntI[i];
    sm[tid] = v; __syncthreads();
    for (int off = 1; off < 256; off <<= 1) {
        int t = (tid >= off) ? sm[tid - off] : 0;
        __syncthreads();
        sm[tid] += t;
        __syncthreads();
    }
    lscan[i] = sm[tid] - v;
    if (tid == 255) bsum[blockIdx.x] = sm[tid];
}

__global__ void k_scan2(const int* __restrict__ bsum, int* __restrict__ bbase) {
    __shared__ int sm[512];
    int tid = threadIdx.x;
    int v = bsum[tid];
    sm[tid] = v; __syncthreads();
    for (int off = 1; off < 512; off <<= 1) {
        int t = (tid >= off) ? sm[tid - off] : 0;
        __syncthreads();
        sm[tid] += t;
        __syncthreads();
    }
    bbase[tid] = sm[tid] - v;
}

// ---------------- fill CSR point lists ----------------
__global__ void k_fill(const int* __restrict__ vidx, const int* __restrict__ lscan,
                       const int* __restrict__ bbase, int* __restrict__ rank,
                       int* __restrict__ plist) {
    int i = blockIdx.x * 256 + threadIdx.x;  // B*NN
    int b = i >> 12, n = i & (NN - 1);
    int flat = b * R3 + vidx[i];
    int r = atomicAdd(&rank[flat], 1);
    plist[bbase[flat >> 8] + lscan[flat] + r] = n;
}

// ---------------- features: cf f32 -> cl f32 (featT) + cf bf16 (featb), fused ----------------
__global__ void k_pfeat(const float* __restrict__ feat, float* __restrict__ featT,
                        ushort_t* __restrict__ featb) {
    __shared__ float t[64][65];
    int b = blockIdx.y, n0 = blockIdx.x * 64, tid = threadIdx.x;
    int q = tid >> 6, nl = tid & 63;
    #pragma unroll
    for (int k = 0; k < 16; k++) {
        int c = q * 16 + k;
        float v = feat[((size_t)(b * CI + c)) * NN + n0 + nl];
        t[nl][c] = v;
        featb[((size_t)(b * CI + c)) * NN + n0 + nl] = f2bf(v);
    }
    __syncthreads();
    #pragma unroll
    for (int k = 0; k < 16; k++) {
        int n = q * 16 + k;
        featT[((size_t)b * NN + n0 + n) * 64 + nl] = t[n][nl];
    }
}

// ---------------- segmented gather-mean -> gT bf16 cl ----------------
__global__ __launch_bounds__(256) void k_gather(const float* __restrict__ featT,
                                                const int* __restrict__ cntI,
                                                const int* __restrict__ lscan,
                                                const int* __restrict__ bbase,
                                                const int* __restrict__ plist,
                                                ushort_t* __restrict__ gT) {
    int wv = threadIdx.x >> 6, lane = threadIdx.x & 63;
    int vbase = blockIdx.x * 32 + wv * 8;
    for (int k = 0; k < 8; k++) {
        int flat = vbase + k;
        int count = cntI[flat];
        float s = 0.0f;
        if (count > 0) {
            int b = flat >> 15;
            int start = bbase[flat >> 8] + lscan[flat];
            for (int j = 0; j < count; j++) {
                int n = plist[start + j];
                s += featT[((size_t)b * NN + n) * 64 + lane];
            }
            s *= 1.0f / (float)count;
        }
        gT[(size_t)flat * 64 + lane] = f2bf(s);
    }
}

// ---------------- weight transform (both convs in one launch) ----------------
__global__ void k_tws(const float* __restrict__ w1, const float* __restrict__ w2,
                      ushort_t* __restrict__ wS1, ushort_t* __restrict__ wS2) {
    int i = blockIdx.x * 256 + threadIdx.x;  // 221184
    const float* w = (i < 110592) ? w1 : w2;
    ushort_t* wS = (i < 110592) ? wS1 : wS2;
    int j = (i < 110592) ? i : i - 110592;
    int cis = j & 31, co = (j >> 5) & 63;
    int dx = (j >> 11) % 3, cih = (j / 6144) & 1, dzdy = j / 12288;
    int k = dzdy * 3 + dx, ci = cih * 32 + cis;
    wS[j] = f2bf(w[((size_t)co * CI + ci) * 27 + k]);
}

// ---------------- weight fold/transposes for 1x1 kernels (+ accs zeroing) ----------------
__global__ void k_fold(const float* __restrict__ wp, const float* __restrict__ wfu,
                       const float* __restrict__ wf, const float* __restrict__ bf,
                       const float* __restrict__ bfu,
                       float* __restrict__ wpT, float* __restrict__ wfuT,
                       float* __restrict__ bC, float* __restrict__ accs) {
    int i = blockIdx.x * 256 + threadIdx.x;
    if (i < 4096) {
        int c = i >> 6, o = i & 63;
        wpT[c * 64 + o] = wp[o * 64 + c];
    } else if (i < 12288) {
        int j = i - 4096;
        int c = j >> 6, o = j & 63;
        wfuT[c * 64 + o] = wfu[(size_t)o * 192 + c];
    } else if (i < 16384) {
        int j = i - 12288;
        int c = j >> 6, o = j & 63;
        float s = 0;
        for (int k = 0; k < 64; k++)
            s += wfu[(size_t)o * 192 + 128 + k] * wf[(size_t)k * 64 + c];
        wfuT[(128 + c) * 64 + o] = s;
    } else if (i < 16448) {
        int o = i - 16384;
        float s = bfu[o];
        for (int k = 0; k < 64; k++)
            s += wfu[(size_t)o * 192 + 128 + k] * bf[k];
        bC[o] = s;
    } else if (i < 16960) {
        accs[i - 16448] = 0.0f;
    }
}

// ---------------- BN(from accs) + lrelu, bf16 -> bf16 (cl -> cl) ----------------
__global__ void k_bncast2(const ushort_t* __restrict__ x, const float* __restrict__ accs,
                          const float* __restrict__ g, const float* __restrict__ be,
                          float invcnt, float slope, ushort_t* __restrict__ o) {
    size_t i = (size_t)blockIdx.x * 256 + threadIdx.x;  // over B*R3*64/8
    int c0 = (int)((i * 8) & 63);
    float sc[8], sh[8];
    #pragma unroll
    for (int j = 0; j < 8; j++) {
        int c = c0 + j;
        float mean = accs[2 * c] * invcnt;
        float var = accs[2 * c + 1] * invcnt - mean * mean;
        float scale = g[c] * rsqrtf(var + 1e-4f);
        sc[j] = scale;
        sh[j] = be[c] - mean * scale;
    }
    uint4 in = ((const uint4*)x)[i];
    unsigned iv[4] = {in.x, in.y, in.z, in.w};
    unsigned pk[4];
    #pragma unroll
    for (int j = 0; j < 4; j++) {
        float u0 = bf2f((unsigned short)(iv[j] & 0xFFFF)) * sc[2 * j] + sh[2 * j];
        float u1 = bf2f((unsigned short)(iv[j] >> 16)) * sc[2 * j + 1] + sh[2 * j + 1];
        u0 = u0 > 0 ? u0 : slope * u0;
        u1 = u1 > 0 ? u1 : slope * u1;
        pk[j] = (unsigned)f2bf(u0) | ((unsigned)f2bf(u1) << 16);
    }
    ((uint4*)o)[i] = make_uint4(pk[0], pk[1], pk[2], pk[3]);
}

// ---------------- LDS-staged MFMA conv3d 3x3x3, 4-row tiles, 1024 blocks ----------------
// lin = 6 rows x 32x x 64c (24576B), lw dbuf (24576B) -> 49152B total, 3 blocks/CU.
template <int OUTBF16>
__global__ __launch_bounds__(256) void k_convlds(const ushort_t* __restrict__ gT,
                                                 const ushort_t* __restrict__ wS,
                                                 void* __restrict__ outP,
                                                 float* __restrict__ accs) {
    __shared__ char smem[49152];
    ushort_t* lin = (ushort_t*)smem;             // 24576B: 1536 granules (6 rows x 256)
    ushort_t* lwp = (ushort_t*)(smem + 24576);   // 2 x 12288B weights
    int bid = blockIdx.x;
    int wgid = (bid & 7) * 128 + (bid >> 3);     // 1024 blocks, 8 XCDs x 128
    int yt = wgid & 7, z0 = (wgid >> 3) & 31, b = wgid >> 8;
    int tid = threadIdx.x;
    int w = __builtin_amdgcn_readfirstlane(tid >> 6);
    int lane = tid & 63, l15 = lane & 15, l4 = lane >> 4;
    int y0 = yt * 4;
    const ushort_t* gTb = gT + (size_t)b * R3 * 64;

    // wave w owns local row w; frags f in {0,1}: x = f*16 + l15
    int voxF[2];
    #pragma unroll
    for (int f = 0; f < 2; f++)
        voxF[f] = w * 32 + f * 16 + l15 - 1;
    bool xlo_ok = (l15 != 0), xhi_ok = (l15 != 15);

    int lsw = lane ^ ((lane >> 3) & 7);
    int wsz8 = ((l15 * 4 + l4) ^ ((l15 >> 1) & 7)) * 8;

    const v8s vzero = {};
    v4f acc[4][2];
    #pragma unroll
    for (int m = 0; m < 4; m++)
        #pragma unroll
        for (int f = 0; f < 2; f++)
            acc[m][f] = (v4f){0.0f, 0.0f, 0.0f, 0.0f};

#define WSTAGE(s)                                                              \
    do {                                                                       \
        const ushort_t* _src = wS + (size_t)(s) * 6144;                        \
        ushort_t* _dst = lwp + ((s) & 1) * 6144;                               \
        _Pragma("unroll") for (int _i = 0; _i < 3; _i++) {                     \
            int _pb = _i * 256 + w * 64;                                       \
            gll16(_src + (size_t)(_pb + lsw) * 8, _dst + (size_t)(_pb + lane) * 8); \
        }                                                                      \
    } while (0)

#define ISTAGE(dz)                                                             \
    do {                                                                       \
        int _zp = z0 - 1 + (dz);                                               \
        if (_zp < 0 || _zp > 31) {                                             \
            _Pragma("unroll") for (int _q = 0; _q < 6; _q++)                   \
                *(v8s*)&lin[(size_t)(_q * 256 + tid) * 8] = vzero;             \
        } else {                                                               \
            if (yt == 0) *(v8s*)&lin[(size_t)tid * 8] = vzero;                 \
            if (yt == 7) *(v8s*)&lin[(size_t)(1280 + tid) * 8] = vzero;        \
            const ushort_t* _pb = gTb + ((size_t)_zp * 1024 + (size_t)(y0 - 1) * 32) * 64; \
            int _g0 = (yt == 0) ? 256 : 0;                                     \
            int _nc = 6 - (yt == 0) - (yt == 7);                               \
            for (int _i = 0; _i < _nc; _i++) {                                 \
                int _pbase = _g0 + _i * 256 + w * 64;                          \
                int _p = _pbase + lane;                                        \
                int _vx = _p >> 3, _js = _p & 7;                               \
                int _sg = _vx * 8 + (_js ^ (_vx & 7));                         \
                gll16(_pb + (size_t)_sg * 8, lin + (size_t)_pbase * 8);        \
            }                                                                  \
        }                                                                      \
    } while (0)

    WSTAGE(0);
    for (int s = 0; s < 18; s++) {
        int dy = (s / 2) % 3, cih = s & 1;
        asm volatile("s_barrier" ::: "memory");
        if ((s % 6) == 0) ISTAGE(s / 6);
        if (s + 1 < 18) WSTAGE(s + 1);
        if (s + 1 < 18) asm volatile("s_waitcnt vmcnt(3) lgkmcnt(0)" ::: "memory");
        else            asm volatile("s_waitcnt vmcnt(0) lgkmcnt(0)" ::: "memory");
        asm volatile("s_barrier" ::: "memory");

        const ushort_t* lwb = lwp + (s & 1) * 6144;
        #pragma unroll
        for (int dx = 0; dx < 3; dx++) {
            v8s Bf[2];
            #pragma unroll
            for (int f = 0; f < 2; f++) {
                int vox = voxF[f] + dy * 32 + dx;
                int g = vox * 8 + ((cih * 4 + l4) ^ (vox & 7));
                int bix = g * 16;
                bix = bix < 0 ? 0 : bix;
                v8s vb = *(const v8s*)((const char*)lin + bix);
                bool ok = (dx == 0 && f == 0) ? xlo_ok :
                          (dx == 2 && f == 1) ? xhi_ok : true;
                Bf[f] = ok ? vb : vzero;
            }
            const ushort_t* ap = lwb + dx * 2048 + wsz8;
            #pragma unroll
            for (int m = 0; m < 4; m++) {
                v8s Af = *(const v8s*)(ap + m * 512);
                #pragma unroll
                for (int f = 0; f < 2; f++)
                    acc[m][f] = __builtin_amdgcn_mfma_f32_16x16x32_bf16(Af, Bf[f], acc[m][f], 0, 0, 0);
            }
        }
    }

    // stores (y = y0 + w; x = f*16 + l15)
    #pragma unroll
    for (int m = 0; m < 4; m++) {
        #pragma unroll
        for (int f = 0; f < 2; f++) {
            int y = y0 + w;
            int x = f * 16 + l15;
            size_t base = ((size_t)b * R3 + z0 * 1024 + y * 32 + x) * 64 + m * 16 + l4 * 4;
            if (OUTBF16) {
                unsigned p0 = (unsigned)f2bf(acc[m][f][0]) | ((unsigned)f2bf(acc[m][f][1]) << 16);
                unsigned p1 = (unsigned)f2bf(acc[m][f][2]) | ((unsigned)f2bf(acc[m][f][3]) << 16);
                *(uint2*)&((ushort_t*)outP)[base] = make_uint2(p0, p1);
            } else {
                float4 o = make_float4(acc[m][f][0], acc[m][f][1], acc[m][f][2], acc[m][f][3]);
                *(float4*)&((float*)outP)[base] = o;
            }
        }
    }

    // fused BN-stats (sbuf overlays full smem: 33792B <= 49152B; stride-33 conflict-free)
    __syncthreads();
    float* sbuf = (float*)smem;
    #pragma unroll
    for (int m = 0; m < 4; m++)
        #pragma unroll
        for (int r = 0; r < 4; r++) {
            float s = 0, q = 0;
            #pragma unroll
            for (int f = 0; f < 2; f++) {
                float v = acc[m][f][r];
                s += v; q += v * v;
            }
            sbuf[tid * 33 + (m * 4 + r) * 2] = s;
            sbuf[tid * 33 + (m * 4 + r) * 2 + 1] = q;
        }
    __syncthreads();
    if (tid < 128) {
        int co = tid >> 1, val = tid & 1;
        int m = co >> 4, cl4 = (co >> 2) & 3, r = co & 3;
        float a = 0;
        for (int w2 = 0; w2 < 4; w2++)
            for (int l = 0; l < 16; l++)
                a += sbuf[(w2 * 64 + cl4 * 16 + l) * 33 + (m * 4 + r) * 2 + val];
        atomicAdd(&accs[2 * co + val], a);
    }
#undef WSTAGE
#undef ISTAGE
}

// reduce 256 partials per channel
__global__ void k_bnfin2(const float* __restrict__ pst, const float* __restrict__ g,
                         const float* __restrict__ be, float* __restrict__ stats,
                         float invcnt) {
    int c = blockIdx.x, tid = threadIdx.x;
    __shared__ float rs[256], rq[256];
    rs[tid] = pst[(c * 256 + tid) * 2];
    rq[tid] = pst[(c * 256 + tid) * 2 + 1];
    __syncthreads();
    for (int off = 128; off > 0; off >>= 1) {
        if (tid < off) { rs[tid] += rs[tid + off]; rq[tid] += rq[tid + off]; }
        __syncthreads();
    }
    if (tid == 0) {
        float mean = rs[0] * invcnt;
        float var = rq[0] * invcnt - mean * mean;
        float sc = g[c] * rsqrtf(var + 1e-4f);
        stats[2 * c] = sc;
        stats[2 * c + 1] = be[c] - mean * sc;
    }
}

__global__ void k_bn_act(const float* __restrict__ x, const float* __restrict__ stats,
                         float* __restrict__ out, int shift, float slope) {
    size_t i = (size_t)blockIdx.x * 256 + threadIdx.x;
    int c = (int)((i >> shift) & 63);
    float sc = stats[2 * c], sh = stats[2 * c + 1];
    float4 v = ((const float4*)x)[i];
    v.x = v.x * sc + sh; v.y = v.y * sc + sh; v.z = v.z * sc + sh; v.w = v.w * sc + sh;
    v.x = v.x > 0 ? v.x : slope * v.x;
    v.y = v.y > 0 ? v.y : slope * v.y;
    v.z = v.z > 0 ? v.z : slope * v.z;
    v.w = v.w > 0 ? v.w : slope * v.w;
    ((float4*)out)[i] = v;
}

// ---------------- devoxelize (bf16 grid), BN(from accs)+lrelu fused ----------------
__global__ void k_devox2(const ushort_t* __restrict__ gcl, const float* __restrict__ accs,
                         const float* __restrict__ g, const float* __restrict__ be,
                         float invcnt, const float* __restrict__ nc,
                         float* __restrict__ out) {
    int b = blockIdx.y;
    int tid = threadIdx.x, p = tid >> 4, q = tid & 15;
    int n = blockIdx.x * 16 + p;
    float x = nc[((size_t)b * 3 + 0) * NN + n];
    float y = nc[((size_t)b * 3 + 1) * NN + n];
    float z = nc[((size_t)b * 3 + 2) * NN + n];
    float fx = floorf(x), fy = floorf(y), fz = floorf(z);
    int lx = (int)fx, ly = (int)fy, lz = (int)fz;
    int hx = min(lx + 1, RR - 1), hy = min(ly + 1, RR - 1), hz = min(lz + 1, RR - 1);
    float frx = x - fx, fry = y - fy, frz = z - fz;
    int xx[2] = {lx, hx}, yy[2] = {ly, hy}, zz[2] = {lz, hz};
    float wx[2] = {1.0f - frx, frx}, wy[2] = {1.0f - fry, fry}, wz[2] = {1.0f - frz, frz};
    float sc[4], sh[4];
    #pragma unroll
    for (int j = 0; j < 4; j++) {
        int c = q * 4 + j;
        float mean = accs[2 * c] * invcnt;
        float var = accs[2 * c + 1] * invcnt - mean * mean;
        float scale = g[c] * rsqrtf(var + 1e-4f);
        sc[j] = scale;
        sh[j] = be[c] - mean * scale;
    }
    float a0 = 0, a1 = 0, a2 = 0, a3 = 0;
    #pragma unroll
    for (int dx = 0; dx < 2; dx++)
        #pragma unroll
        for (int dy = 0; dy < 2; dy++)
            #pragma unroll
            for (int dz = 0; dz < 2; dz++) {
                int idx = (xx[dx] * RR + yy[dy]) * RR + zz[dz];
                float wt = wx[dx] * wy[dy] * wz[dz];
                uint2 pv = *(const uint2*)&gcl[((size_t)b * R3 + idx) * 64 + q * 4];
                float v0 = bf2f((unsigned short)(pv.x & 0xFFFF));
                float v1 = bf2f((unsigned short)(pv.x >> 16));
                float v2 = bf2f((unsigned short)(pv.y & 0xFFFF));
                float v3 = bf2f((unsigned short)(pv.y >> 16));
                float u0 = v0 * sc[0] + sh[0]; u0 = u0 > 0 ? u0 : 0.1f * u0;
                float u1 = v1 * sc[1] + sh[1]; u1 = u1 > 0 ? u1 : 0.1f * u1;
                float u2 = v2 * sc[2] + sh[2]; u2 = u2 > 0 ? u2 : 0.1f * u2;
                float u3 = v3 * sc[3] + sh[3]; u3 = u3 > 0 ? u3 : 0.1f * u3;
                a0 += wt * u0; a1 += wt * u1; a2 += wt * u2; a3 += wt * u3;
            }
    out[((size_t)(b * 64 + q * 4 + 0)) * NN + n] = a0;
    out[((size_t)(b * 64 + q * 4 + 1)) * NN + n] = a1;
    out[((size_t)(b * 64 + q * 4 + 2)) * NN + n] = a2;
    out[((size_t)(b * 64 + q * 4 + 3)) * NN + n] = a3;
}

// ---------------- fuzzy attention (MFMA): ring-4 A staging, counted vmcnt ----------------
__global__ __launch_bounds__(256) void k_fuzzym(const float* __restrict__ coords,
                                                const ushort_t* __restrict__ featb,
                                                float* __restrict__ pnum,
                                                float* __restrict__ pden) {
    __shared__ float cm[3][1024];
    __shared__ ushort_t la[4][2048];
    int b = blockIdx.z, mc = blockIdx.y, nt = blockIdx.x;
    int tid = threadIdx.x;
    int w = tid >> 6, lane = tid & 63, l15 = lane & 15, l4 = lane >> 4;
    int m0 = mc * 1024;

    for (int i = tid; i < 1024; i += 256) {
        float a0 = coords[((size_t)b * 3 + 0) * NN + m0 + i];
        float a1 = coords[((size_t)b * 3 + 1) * NN + m0 + i];
        float a2 = coords[((size_t)b * 3 + 2) * NN + m0 + i];
        float inv = 1.0f / fmaxf(sqrtf(a0 * a0 + a1 * a1 + a2 * a2), 1e-12f);
        cm[0][i] = a0 * inv; cm[1][i] = a1 * inv; cm[2][i] = a2 * inv;
    }

    int n = nt * 64 + w * 16 + l15;
    float q0 = coords[((size_t)b * 3 + 0) * NN + n];
    float q1 = coords[((size_t)b * 3 + 1) * NN + n];
    float q2 = coords[((size_t)b * 3 + 2) * NN + n];
    float qi = 10.0f / fmaxf(sqrtf(q0 * q0 + q1 * q1 + q2 * q2), 1e-12f);
    q0 *= qi; q1 *= qi; q2 *= qi;

    int srow = tid >> 2, sslot = tid & 3;
    int g0 = sslot ^ ((srow >> 1) & 3);
    const ushort_t* fb = featb + (size_t)b * 64 * NN + m0;
    const ushort_t* sbase = fb + (size_t)srow * NN + g0 * 8;
    int rsw = (l15 >> 1) & 3;

    v4f acc[4];
    #pragma unroll
    for (int cb = 0; cb < 4; cb++) acc[cb] = (v4f){0.0f, 0.0f, 0.0f, 0.0f};
    float den = 0.0f;

    gll16(sbase, &la[0][(size_t)tid * 8]);
    gll16(sbase + 32, &la[1][(size_t)tid * 8]);
    gll16(sbase + 64, &la[2][(size_t)tid * 8]);
    __syncthreads();

    for (int t = 0; t < 32; t++) {
        int cur = t & 3;
        asm volatile("s_waitcnt vmcnt(2)" ::: "memory");
        __syncthreads();
        if (t + 3 < 32)
            gll16(sbase + (t + 3) * 32, &la[(t + 3) & 3][(size_t)tid * 8]);

        int mo = t * 32 + l4 * 8;
        float e[8];
        #pragma unroll
        for (int jj = 0; jj < 2; jj++) {
            float4 x0 = *(const float4*)&cm[0][mo + jj * 4];
            float4 x1 = *(const float4*)&cm[1][mo + jj * 4];
            float4 x2 = *(const float4*)&cm[2][mo + jj * 4];
            e[jj * 4 + 0] = __expf(q0 * x0.x + q1 * x1.x + q2 * x2.x);
            e[jj * 4 + 1] = __expf(q0 * x0.y + q1 * x1.y + q2 * x2.y);
            e[jj * 4 + 2] = __expf(q0 * x0.z + q1 * x1.z + q2 * x2.z);
            e[jj * 4 + 3] = __expf(q0 * x0.w + q1 * x1.w + q2 * x2.w);
        }
        den += ((e[0] + e[1]) + (e[2] + e[3])) + ((e[4] + e[5]) + (e[6] + e[7]));
        union { __hip_bfloat162 h[4]; v8s v; } pk;
        pk.h[0] = __float22bfloat162_rn(make_float2(e[0], e[1]));
        pk.h[1] = __float22bfloat162_rn(make_float2(e[2], e[3]));
        pk.h[2] = __float22bfloat162_rn(make_float2(e[4], e[5]));
        pk.h[3] = __float22bfloat162_rn(make_float2(e[6], e[7]));
        #pragma unroll
        for (int cb = 0; cb < 4; cb++) {
            v8s A = *(const v8s*)&la[cur][(size_t)((cb * 16 + l15) * 4 + (l4 ^ rsw)) * 8];
            acc[cb] = __builtin_amdgcn_mfma_f32_16x16x32_bf16(A, pk.v, acc[cb], 0, 0, 0);
        }
        __syncthreads();
    }

    den += __shfl_xor(den, 16);
    den += __shfl_xor(den, 32);

    size_t obase = ((size_t)(b * 4 + mc)) * 64 * NN;
    #pragma unroll
    for (int cb = 0; cb < 4; cb++)
        #pragma unroll
        for (int r = 0; r < 4; r++)
            pnum[obase + (size_t)(cb * 16 + l4 * 4 + r) * NN + n] = acc[cb][r];
    if (l4 == 0) pden[((size_t)(b * 4 + mc)) * NN + n] = den;
}

__global__ void k_combine2(const float* __restrict__ pnum, const float* __restrict__ pden,
                           float* __restrict__ fzf) {
    int i = blockIdx.x * 256 + threadIdx.x;
    int b = i >> 18, c = (i >> 12) & 63, n = i & 4095;
    float num = 0, den = 0;
    #pragma unroll
    for (int ch = 0; ch < 4; ch++) {
        num += pnum[((size_t)(b * 4 + ch) * 64 + c) * NN + n];
        den += pden[((size_t)(b * 4 + ch)) * NN + n];
    }
    fzf[((size_t)(b * 64 + c)) * NN + n] = num / den;
}

// ---------------- 1x1 convs: thread = 4n x 1o, partial stats ----------------
__global__ __launch_bounds__(256) void k_1x1s(const float* __restrict__ in,
                                              const float* __restrict__ wT,
                                              const float* __restrict__ bias,
                                              float* __restrict__ out,
                                              float* __restrict__ pst) {
    int b = blockIdx.z, ob = blockIdx.y, bx = blockIdx.x;
    int tid = threadIdx.x;
    int q = tid & 15, o = ob * 16 + (tid >> 4);
    int n = bx * 64 + q * 4;
    const float* src = in + (size_t)b * 64 * NN + n;
    const float* wp_ = wT + o;
    v4f acc = {0, 0, 0, 0};
    #pragma unroll 8
    for (int c = 0; c < 64; c++) {
        float4 x = *(const float4*)&src[(size_t)c * NN];
        float w = wp_[c * 64];
        acc[0] += x.x * w; acc[1] += x.y * w; acc[2] += x.z * w; acc[3] += x.w * w;
    }
    float bv = bias[o];
    float s = 0, q2 = 0;
    float4 ov;
    float* op = (float*)&ov;
    #pragma unroll
    for (int v = 0; v < 4; v++) {
        float val = acc[v] + bv;
        op[v] = val;
        s += val; q2 += val * val;
    }
    *(float4*)&out[((size_t)(b * 64 + o)) * NN + n] = ov;
    #pragma unroll
    for (int off = 1; off < 16; off <<= 1) {
        s += __shfl_xor(s, off);
        q2 += __shfl_xor(q2, off);
    }
    if (q == 0) {
        int part = bx * 4 + b;
        pst[(o * 256 + part) * 2] = s;
        pst[(o * 256 + part) * 2 + 1] = q2;
    }
}

// fusion: segA=vox, segB=pt(BN+relu on the fly), segC=fzf (pre-combined)
__global__ __launch_bounds__(256) void k_1x1f(const float* __restrict__ vox,
                                              const float* __restrict__ pt,
                                              const float* __restrict__ fzf,
                                              const float* __restrict__ bnB,
                                              const float* __restrict__ wfuT,
                                              const float* __restrict__ bC,
                                              float* __restrict__ out,
                                              float* __restrict__ pst) {
    int b = blockIdx.z, ob = blockIdx.y, bx = blockIdx.x;
    int tid = threadIdx.x;
    int q = tid & 15, o = ob * 16 + (tid >> 4);
    int n = bx * 64 + q * 4;
    const float* srcA = vox + (size_t)b * 64 * NN + n;
    const float* srcB = pt + (size_t)b * 64 * NN + n;
    const float* srcC = fzf + (size_t)b * 64 * NN + n;
    const float* wA = wfuT + o;
    v4f acc = {0, 0, 0, 0};
    #pragma unroll 8
    for (int c = 0; c < 64; c++) {
        float4 x = *(const float4*)&srcA[(size_t)c * NN];
        float w = wA[c * 64];
        acc[0] += x.x * w; acc[1] += x.y * w; acc[2] += x.z * w; acc[3] += x.w * w;
    }
    #pragma unroll 8
    for (int c = 0; c < 64; c++) {
        float4 x = *(const float4*)&srcB[(size_t)c * NN];
        float sc = bnB[2 * c], sh = bnB[2 * c + 1];
        float w = wA[(64 + c) * 64];
        float x0 = fmaxf(x.x * sc + sh, 0.0f), x1 = fmaxf(x.y * sc + sh, 0.0f);
        float x2 = fmaxf(x.z * sc + sh, 0.0f), x3 = fmaxf(x.w * sc + sh, 0.0f);
        acc[0] += x0 * w; acc[1] += x1 * w; acc[2] += x2 * w; acc[3] += x3 * w;
    }
    #pragma unroll 8
    for (int c = 0; c < 64; c++) {
        float4 x = *(const float4*)&srcC[(size_t)c * NN];
        float w = wA[(128 + c) * 64];
        acc[0] += x.x * w; acc[1] += x.y * w; acc[2] += x.z * w; acc[3] += x.w * w;
    }
    float bv = bC[o];
    float s = 0, q2 = 0;
    float4 ov;
    float* op = (float*)&ov;
    #pragma unroll
    for (int v = 0; v < 4; v++) {
        float val = acc[v] + bv;
        op[v] = val;
        s += val; q2 += val * val;
    }
    *(float4*)&out[((size_t)(b * 64 + o)) * NN + n] = ov;
    #pragma unroll
    for (int off = 1; off < 16; off <<= 1) {
        s += __shfl_xor(s, off);
        q2 += __shfl_xor(q2, off);
    }
    if (q == 0) {
        int part = bx * 4 + b;
        pst[(o * 256 + part) * 2] = s;
        pst[(o * 256 + part) * 2 + 1] = q2;
    }
}

// ---------------- launcher ----------------
extern "C" void kernel_launch(void* const* d_in, const int* in_sizes, int n_in,
                              void* d_out, int out_size, void* d_ws, size_t ws_size,
                              hipStream_t stream) {
    const float* features = (const float*)d_in[0];
    const float* coords = (const float*)d_in[1];
    const float* w1 = (const float*)d_in[2];
    const float* g1 = (const float*)d_in[4];
    const float* be1 = (const float*)d_in[5];
    const float* w2 = (const float*)d_in[6];
    const float* g2 = (const float*)d_in[8];
    const float* be2 = (const float*)d_in[9];
    const float* wp = (const float*)d_in[10];
    const float* bp = (const float*)d_in[11];
    const float* gp = (const float*)d_in[12];
    const float* bep = (const float*)d_in[13];
    const float* wf = (const float*)d_in[14];
    const float* bf = (const float*)d_in[15];
    const float* wfu = (const float*)d_in[16];
    const float* bfu = (const float*)d_in[17];
    const float* gfu = (const float*)d_in[18];
    const float* befu = (const float*)d_in[19];

    float* ws = (float*)d_ws;
    float* nc = ws;                        // 49152
    int* vidx = (int*)(ws + 49152);        // 16384 ints
    int* cntI = (int*)(ws + 65536);        // 131072 ints (pden overlays later)
    float* pden = ws + 65536;
    float* gridCL = ws + 196608;           // conv outputs (bf16 raw both convs)
    ushort_t* gTraw = (ushort_t*)gridCL;
    int* rank = (int*)(ws + 196608);       // overlay (pre-conv only)
    int* lscan = (int*)(ws + 327680);
    int* bsum = (int*)(ws + 458752);
    int* bbase = (int*)(ws + 459264);
    int* plist = (int*)(ws + 459776);
    float* featT = ws + 476160;            // 1048576 floats
    float* gTpool = ws + 8585216;          // gT bf16 / pnum / pstB
    ushort_t* gT = (ushort_t*)gTpool;
    float* pnum = gTpool;                  // 4,194,304 floats
    float* pstB = gTpool + 4194304;        // 32768 floats (disjoint from pnum)
    float* stats = ws + 16973824;
    float* voxreg = ws + 16974336;
    ushort_t* wS1 = (ushort_t*)voxreg;
    ushort_t* wS2 = wS1 + 110592;
    float* vox = voxreg;
    float* pt = ws + 18022912;
    float* fzf = ws + 19071488;
    float* wpT = ws + 20120064;
    float* wfuT = wpT + 4096;
    float* bC = wfuT + 12288;
    float* fpre = ws + 21168640;
    ushort_t* featb = (ushort_t*)fpre;
    float* accs = ws + 22217216;

    float* out = (float*)d_out;

    hipMemsetAsync(cntI, 0, (size_t)131072 * 4, stream);
    hipMemsetAsync(rank, 0, (size_t)131072 * 4, stream);

    // prep (independent); k_fold also zeroes accs
    k_fold<<<67, 256, 0, stream>>>(wp, wfu, wf, bf, bfu, wpT, wfuT, bC, accs);
    k_pfeat<<<dim3(64, BB), 256, 0, stream>>>(features, featT, featb);
    k_tws<<<864, 256, 0, stream>>>(w1, w2, wS1, wS2);

    // voxelization: CSR gather-mean
    k_nc<<<BB, 256, 0, stream>>>(coords, nc, vidx, cntI);
    k_scan1<<<512, 256, 0, stream>>>(cntI, lscan, bsum);
    k_scan2<<<1, 512, 0, stream>>>(bsum, bbase);
    k_fill<<<BB * NN / 256, 256, 0, stream>>>(vidx, lscan, bbase, rank, plist);
    k_gather<<<4096, 256, 0, stream>>>(featT, cntI, lscan, bbase, plist, gT);

    // voxel branch (both convs bf16-out; 1024-block 4-row tiles)
    k_convlds<1><<<1024, 256, 0, stream>>>(gT, wS1, gTraw, accs);
    k_bncast2<<<BB * R3 * 64 / 8 / 256, 256, 0, stream>>>(gTraw, accs, g1, be1,
                                                          1.0f / (BB * R3), 0.1f, gT);
    k_convlds<1><<<1024, 256, 0, stream>>>(gT, wS2, gTraw, accs + 128);
    k_devox2<<<dim3(NN / 16, BB), 256, 0, stream>>>(gTraw, accs + 128, g2, be2,
                                                    1.0f / (BB * R3), nc, vox);

    // fuzzy branch
    k_fuzzym<<<dim3(64, 4, BB), 256, 0, stream>>>(coords, featb, pnum, pden);
    k_combine2<<<BB * 64 * NN / 256, 256, 0, stream>>>(pnum, pden, fzf);

    // point branch
    k_1x1s<<<dim3(NN / 64, 4, BB), 256, 0, stream>>>(features, wpT, bp, pt, pstB);
    k_bnfin2<<<64, 256, 0, stream>>>(pstB, gp, bep, stats + 256, 1.0f / (BB * NN));

    // fusion
    k_1x1f<<<dim3(NN / 64, 4, BB), 256, 0, stream>>>(vox, pt, fzf, stats + 256, wfuT, bC,
                                                     fpre, pstB);
    k_bnfin2<<<64, 256, 0, stream>>>(pstB, gfu, befu, stats + 384, 1.0f / (BB * NN));
    k_bn_act<<<BB * 64 * NN / 4 / 256, 256, 0, stream>>>(fpre, stats + 384, out, 10, 0.0f);

    hipMemcpyAsync(out + (size_t)BB * CO * NN, coords, (size_t)BB * 3 * NN * 4,
                   hipMemcpyDeviceToDevice, stream);
}

// Round 21
// 269.940 us; speedup vs baseline: 1.0782x; 1.0782x over previous
//
#include <hip/hip_runtime.h>
#include <hip/hip_bf16.h>
#include <math.h>

#define RR 32
#define R3 32768
#define BB 4
#define CI 64
#define CO 64
#define NN 4096

typedef short v8s __attribute__((ext_vector_type(8)));
typedef float v4f __attribute__((ext_vector_type(4)));
typedef unsigned short ushort_t;

__device__ __forceinline__ unsigned short f2bf(float f) {
    unsigned int u = __float_as_uint(f);
    unsigned int r = (u + 0x7FFFu + ((u >> 16) & 1u)) >> 16;
    return (unsigned short)r;
}
__device__ __forceinline__ float bf2f(unsigned short h) {
    return __uint_as_float((unsigned int)h << 16);
}

__device__ __forceinline__ void gll16(const void* g, void* l) {
    __builtin_amdgcn_global_load_lds((const __attribute__((address_space(1))) unsigned int*)g,
                                     (__attribute__((address_space(3))) unsigned int*)l, 16, 0, 0);
}

// ---------------- block reduce helpers ----------------
__device__ __forceinline__ float blockReduceSum(float v, float* sm) {
    int tid = threadIdx.x;
    sm[tid] = v; __syncthreads();
    for (int off = 128; off > 0; off >>= 1) {
        if (tid < off) sm[tid] += sm[tid + off];
        __syncthreads();
    }
    float r = sm[0]; __syncthreads();
    return r;
}
__device__ __forceinline__ float blockReduceMax(float v, float* sm) {
    int tid = threadIdx.x;
    sm[tid] = v; __syncthreads();
    for (int off = 128; off > 0; off >>= 1) {
        if (tid < off) sm[tid] = fmaxf(sm[tid], sm[tid + off]);
        __syncthreads();
    }
    float r = sm[0]; __syncthreads();
    return r;
}

// ---------------- voxel coords + fused voxel count ----------------
__global__ void k_nc(const float* __restrict__ coords, float* __restrict__ nc,
                     int* __restrict__ vidx, int* __restrict__ cntI) {
    int b = blockIdx.x, tid = threadIdx.x;
    __shared__ float sm[256];
    const float* cb = coords + (size_t)b * 3 * NN;
    float s0 = 0, s1 = 0, s2 = 0;
    for (int n = tid; n < NN; n += 256) {
        s0 += cb[n]; s1 += cb[NN + n]; s2 += cb[2 * NN + n];
    }
    float m0 = blockReduceSum(s0, sm) * (1.0f / NN);
    float m1 = blockReduceSum(s1, sm) * (1.0f / NN);
    float m2 = blockReduceSum(s2, sm) * (1.0f / NN);
    float mx = 0;
    for (int n = tid; n < NN; n += 256) {
        float dx = cb[n] - m0, dy = cb[NN + n] - m1, dz = cb[2 * NN + n] - m2;
        mx = fmaxf(mx, dx * dx + dy * dy + dz * dz);
    }
    mx = blockReduceMax(mx, sm);
    float denom = 2.0f * sqrtf(mx);
    float mean[3] = {m0, m1, m2};
    for (int n = tid; n < NN; n += 256) {
        int vi[3];
        #pragma unroll
        for (int ax = 0; ax < 3; ax++) {
            float x = (cb[ax * NN + n] - mean[ax]) / denom + 0.5f;
            x = x * RR;
            x = fminf(fmaxf(x, 0.0f), (float)(RR - 1));
            nc[((size_t)b * 3 + ax) * NN + n] = x;
            vi[ax] = (int)rintf(x);
        }
        int idx = (vi[0] * RR + vi[1]) * RR + vi[2];
        vidx[b * NN + n] = idx;
        atomicAdd(&cntI[b * R3 + idx], 1);
    }
}

// ---------------- scan ----------------
__global__ void k_scan1(const int* __restrict__ cntI, int* __restrict__ lscan,
                        int* __restrict__ bsum) {
    __shared__ int sm[256];
    int tid = threadIdx.x;
    int i = blockIdx.x * 256 + tid;
    int v = cntI[i];
    sm[tid] = v; __syncthreads();
    for (int off = 1; off < 256; off <<= 1) {
        int t = (tid >= off) ? sm[tid - off] : 0;
        __syncthreads();
        sm[tid] += t;
        __syncthreads();
    }
    lscan[i] = sm[tid] - v;
    if (tid == 255) bsum[blockIdx.x] = sm[tid];
}

__global__ void k_scan2(const int* __restrict__ bsum, int* __restrict__ bbase) {
    __shared__ int sm[512];
    int tid = threadIdx.x;
    int v = bsum[tid];
    sm[tid] = v; __syncthreads();
    for (int off = 1; off < 512; off <<= 1) {
        int t = (tid >= off) ? sm[tid - off] : 0;
        __syncthreads();
        sm[tid] += t;
        __syncthreads();
    }
    bbase[tid] = sm[tid] - v;
}

// ---------------- fill CSR point lists ----------------
__global__ void k_fill(const int* __restrict__ vidx, const int* __restrict__ lscan,
                       const int* __restrict__ bbase, int* __restrict__ rank,
                       int* __restrict__ plist) {
    int i = blockIdx.x * 256 + threadIdx.x;  // B*NN
    int b = i >> 12, n = i & (NN - 1);
    int flat = b * R3 + vidx[i];
    int r = atomicAdd(&rank[flat], 1);
    plist[bbase[flat >> 8] + lscan[flat] + r] = n;
}

// ---------------- features: cf f32 -> cl f32 (featT) + cf bf16 (featb), fused ----------------
__global__ void k_pfeat(const float* __restrict__ feat, float* __restrict__ featT,
                        ushort_t* __restrict__ featb) {
    __shared__ float t[64][65];
    int b = blockIdx.y, n0 = blockIdx.x * 64, tid = threadIdx.x;
    int q = tid >> 6, nl = tid & 63;
    #pragma unroll
    for (int k = 0; k < 16; k++) {
        int c = q * 16 + k;
        float v = feat[((size_t)(b * CI + c)) * NN + n0 + nl];
        t[nl][c] = v;
        featb[((size_t)(b * CI + c)) * NN + n0 + nl] = f2bf(v);
    }
    __syncthreads();
    #pragma unroll
    for (int k = 0; k < 16; k++) {
        int n = q * 16 + k;
        featT[((size_t)b * NN + n0 + n) * 64 + nl] = t[n][nl];
    }
}

// ---------------- segmented gather-mean -> gT bf16 cl ----------------
__global__ __launch_bounds__(256) void k_gather(const float* __restrict__ featT,
                                                const int* __restrict__ cntI,
                                                const int* __restrict__ lscan,
                                                const int* __restrict__ bbase,
                                                const int* __restrict__ plist,
                                                ushort_t* __restrict__ gT) {
    int wv = threadIdx.x >> 6, lane = threadIdx.x & 63;
    int vbase = blockIdx.x * 32 + wv * 8;
    for (int k = 0; k < 8; k++) {
        int flat = vbase + k;
        int count = cntI[flat];
        float s = 0.0f;
        if (count > 0) {
            int b = flat >> 15;
            int start = bbase[flat >> 8] + lscan[flat];
            for (int j = 0; j < count; j++) {
                int n = plist[start + j];
                s += featT[((size_t)b * NN + n) * 64 + lane];
            }
            s *= 1.0f / (float)count;
        }
        gT[(size_t)flat * 64 + lane] = f2bf(s);
    }
}

// ---------------- weight transform (both convs in one launch) ----------------
__global__ void k_tws(const float* __restrict__ w1, const float* __restrict__ w2,
                      ushort_t* __restrict__ wS1, ushort_t* __restrict__ wS2) {
    int i = blockIdx.x * 256 + threadIdx.x;  // 221184
    const float* w = (i < 110592) ? w1 : w2;
    ushort_t* wS = (i < 110592) ? wS1 : wS2;
    int j = (i < 110592) ? i : i - 110592;
    int cis = j & 31, co = (j >> 5) & 63;
    int dx = (j >> 11) % 3, cih = (j / 6144) & 1, dzdy = j / 12288;
    int k = dzdy * 3 + dx, ci = cih * 32 + cis;
    wS[j] = f2bf(w[((size_t)co * CI + ci) * 27 + k]);
}

// ---------------- weight fold/transposes for 1x1 kernels (+ accs zeroing) ----------------
__global__ void k_fold(const float* __restrict__ wp, const float* __restrict__ wfu,
                       const float* __restrict__ wf, const float* __restrict__ bf,
                       const float* __restrict__ bfu,
                       float* __restrict__ wpT, float* __restrict__ wfuT,
                       float* __restrict__ bC, float* __restrict__ accs) {
    int i = blockIdx.x * 256 + threadIdx.x;
    if (i < 4096) {
        int c = i >> 6, o = i & 63;
        wpT[c * 64 + o] = wp[o * 64 + c];
    } else if (i < 12288) {
        int j = i - 4096;
        int c = j >> 6, o = j & 63;
        wfuT[c * 64 + o] = wfu[(size_t)o * 192 + c];
    } else if (i < 16384) {
        int j = i - 12288;
        int c = j >> 6, o = j & 63;
        float s = 0;
        for (int k = 0; k < 64; k++)
            s += wfu[(size_t)o * 192 + 128 + k] * wf[(size_t)k * 64 + c];
        wfuT[(128 + c) * 64 + o] = s;
    } else if (i < 16448) {
        int o = i - 16384;
        float s = bfu[o];
        for (int k = 0; k < 64; k++)
            s += wfu[(size_t)o * 192 + 128 + k] * bf[k];
        bC[o] = s;
    } else if (i < 16960) {
        accs[i - 16448] = 0.0f;
    }
}

// ---------------- BN(from accs) + lrelu, bf16 -> bf16 (cl -> cl) ----------------
__global__ void k_bncast2(const ushort_t* __restrict__ x, const float* __restrict__ accs,
                          const float* __restrict__ g, const float* __restrict__ be,
                          float invcnt, float slope, ushort_t* __restrict__ o) {
    size_t i = (size_t)blockIdx.x * 256 + threadIdx.x;  // over B*R3*64/8
    int c0 = (int)((i * 8) & 63);
    float sc[8], sh[8];
    #pragma unroll
    for (int j = 0; j < 8; j++) {
        int c = c0 + j;
        float mean = accs[2 * c] * invcnt;
        float var = accs[2 * c + 1] * invcnt - mean * mean;
        float scale = g[c] * rsqrtf(var + 1e-4f);
        sc[j] = scale;
        sh[j] = be[c] - mean * scale;
    }
    uint4 in = ((const uint4*)x)[i];
    unsigned iv[4] = {in.x, in.y, in.z, in.w};
    unsigned pk[4];
    #pragma unroll
    for (int j = 0; j < 4; j++) {
        float u0 = bf2f((unsigned short)(iv[j] & 0xFFFF)) * sc[2 * j] + sh[2 * j];
        float u1 = bf2f((unsigned short)(iv[j] >> 16)) * sc[2 * j + 1] + sh[2 * j + 1];
        u0 = u0 > 0 ? u0 : slope * u0;
        u1 = u1 > 0 ? u1 : slope * u1;
        pk[j] = (unsigned)f2bf(u0) | ((unsigned)f2bf(u1) << 16);
    }
    ((uint4*)o)[i] = make_uint4(pk[0], pk[1], pk[2], pk[3]);
}

// ---------------- LDS-staged MFMA conv3d 3x3x3 (R19 proven config) ----------------
template <int OUTBF16>
__global__ __launch_bounds__(256) void k_convlds(const ushort_t* __restrict__ gT,
                                                 const ushort_t* __restrict__ wS,
                                                 void* __restrict__ outP,
                                                 float* __restrict__ accs) {
    __shared__ ushort_t lin[20480];     // 40960B input plane (sbuf overlays: 33792B <= 40960B)
    __shared__ ushort_t lw[2][6144];    // 2 x 12288B weights
    int bid = blockIdx.x;
    int wgid = (bid & 7) * 64 + (bid >> 3);
    int yt = wgid & 3, z0 = (wgid >> 2) & 31, b = wgid >> 7;
    int tid = threadIdx.x;
    int w = __builtin_amdgcn_readfirstlane(tid >> 6);
    int lane = tid & 63, l15 = lane & 15, l4 = lane >> 4;
    int y0 = yt * 8;
    const ushort_t* gTb = gT + (size_t)b * R3 * 64;

    int voxF[4];
    #pragma unroll
    for (int f = 0; f < 4; f++)
        voxF[f] = (w * 2 + (f >> 1)) * 32 + (f & 1) * 16 + l15 - 1;
    bool xlo_ok = (l15 != 0), xhi_ok = (l15 != 15);

    int lsw = lane ^ ((lane >> 3) & 7);
    int wsz8 = ((l15 * 4 + l4) ^ ((l15 >> 1) & 7)) * 8;

    const v8s vzero = {};
    v4f acc[4][4];
    #pragma unroll
    for (int m = 0; m < 4; m++)
        #pragma unroll
        for (int f = 0; f < 4; f++)
            acc[m][f] = (v4f){0.0f, 0.0f, 0.0f, 0.0f};

#define WSTAGE(s)                                                              \
    do {                                                                       \
        const ushort_t* _src = wS + (size_t)(s) * 6144;                        \
        ushort_t* _dst = lw[(s) & 1];                                          \
        _Pragma("unroll") for (int _i = 0; _i < 3; _i++) {                     \
            int _pb = _i * 256 + w * 64;                                       \
            gll16(_src + (size_t)(_pb + lsw) * 8, _dst + (size_t)(_pb + lane) * 8); \
        }                                                                      \
    } while (0)

#define ISTAGE(dz)                                                             \
    do {                                                                       \
        int _zp = z0 - 1 + (dz);                                               \
        if (_zp < 0 || _zp > 31) {                                             \
            for (int _q = 0; _q < 10; _q++)                                    \
                *(v8s*)&lin[(size_t)(w * 640 + _q * 64 + lane) * 8] = vzero;   \
        } else {                                                               \
            if (yt == 0) *(v8s*)&lin[(size_t)tid * 8] = vzero;                 \
            if (yt == 3) *(v8s*)&lin[(size_t)(2304 + tid) * 8] = vzero;        \
            const ushort_t* _pb = gTb + ((size_t)_zp * 1024 + (size_t)(y0 - 1) * 32) * 64; \
            int _g0 = (yt == 0) ? 256 : 0;                                     \
            int _nc = 10 - (yt == 0) - (yt == 3);                              \
            for (int _i = 0; _i < _nc; _i++) {                                 \
                int _pbase = _g0 + _i * 256 + w * 64;                          \
                int _p = _pbase + lane;                                        \
                int _vx = _p >> 3, _js = _p & 7;                               \
                int _sg = _vx * 8 + (_js ^ (_vx & 7));                         \
                gll16(_pb + (size_t)_sg * 8, lin + (size_t)_pbase * 8);        \
            }                                                                  \
        }                                                                      \
    } while (0)

    WSTAGE(0);
    for (int s = 0; s < 18; s++) {
        int dy = (s / 2) % 3, cih = s & 1;
        asm volatile("s_barrier" ::: "memory");
        if ((s % 6) == 0) ISTAGE(s / 6);
        if (s + 1 < 18) WSTAGE(s + 1);
        if (s + 1 < 18) asm volatile("s_waitcnt vmcnt(3) lgkmcnt(0)" ::: "memory");
        else            asm volatile("s_waitcnt vmcnt(0) lgkmcnt(0)" ::: "memory");
        asm volatile("s_barrier" ::: "memory");

        const ushort_t* lwb = lw[s & 1];
        #pragma unroll
        for (int dx = 0; dx < 3; dx++) {
            v8s Bf[4];
            #pragma unroll
            for (int f = 0; f < 4; f++) {
                int vox = voxF[f] + dy * 32 + dx;
                int g = vox * 8 + ((cih * 4 + l4) ^ (vox & 7));
                int bix = g * 16;
                bix = bix < 0 ? 0 : bix;
                v8s vb = *(const v8s*)((const char*)lin + bix);
                bool ok = (dx == 0 && (f & 1) == 0) ? xlo_ok :
                          (dx == 2 && (f & 1) == 1) ? xhi_ok : true;
                Bf[f] = ok ? vb : vzero;
            }
            const ushort_t* ap = lwb + dx * 2048 + wsz8;
            #pragma unroll
            for (int m = 0; m < 4; m++) {
                v8s Af = *(const v8s*)(ap + m * 512);
                #pragma unroll
                for (int f = 0; f < 4; f++)
                    acc[m][f] = __builtin_amdgcn_mfma_f32_16x16x32_bf16(Af, Bf[f], acc[m][f], 0, 0, 0);
            }
        }
    }

    // stores
    #pragma unroll
    for (int m = 0; m < 4; m++) {
        #pragma unroll
        for (int f = 0; f < 4; f++) {
            int y = y0 + w * 2 + (f >> 1);
            int x = (f & 1) * 16 + l15;
            size_t base = ((size_t)b * R3 + z0 * 1024 + y * 32 + x) * 64 + m * 16 + l4 * 4;
            if (OUTBF16) {
                unsigned p0 = (unsigned)f2bf(acc[m][f][0]) | ((unsigned)f2bf(acc[m][f][1]) << 16);
                unsigned p1 = (unsigned)f2bf(acc[m][f][2]) | ((unsigned)f2bf(acc[m][f][3]) << 16);
                *(uint2*)&((ushort_t*)outP)[base] = make_uint2(p0, p1);
            } else {
                float4 o = make_float4(acc[m][f][0], acc[m][f][1], acc[m][f][2], acc[m][f][3]);
                *(float4*)&((float*)outP)[base] = o;
            }
        }
    }

    // fused BN-stats (sbuf overlays lin; stride-33: conflict-free)
    __syncthreads();
    float* sbuf = (float*)lin;
    #pragma unroll
    for (int m = 0; m < 4; m++)
        #pragma unroll
        for (int r = 0; r < 4; r++) {
            float s = 0, q = 0;
            #pragma unroll
            for (int f = 0; f < 4; f++) {
                float v = acc[m][f][r];
                s += v; q += v * v;
            }
            sbuf[tid * 33 + (m * 4 + r) * 2] = s;
            sbuf[tid * 33 + (m * 4 + r) * 2 + 1] = q;
        }
    __syncthreads();
    if (tid < 128) {
        int co = tid >> 1, val = tid & 1;
        int m = co >> 4, cl4 = (co >> 2) & 3, r = co & 3;
        float a = 0;
        for (int w2 = 0; w2 < 4; w2++)
            for (int l = 0; l < 16; l++)
                a += sbuf[(w2 * 64 + cl4 * 16 + l) * 33 + (m * 4 + r) * 2 + val];
        atomicAdd(&accs[2 * co + val], a);
    }
#undef WSTAGE
#undef ISTAGE
}

// reduce 256 partials per channel
__global__ void k_bnfin2(const float* __restrict__ pst, const float* __restrict__ g,
                         const float* __restrict__ be, float* __restrict__ stats,
                         float invcnt) {
    int c = blockIdx.x, tid = threadIdx.x;
    __shared__ float rs[256], rq[256];
    rs[tid] = pst[(c * 256 + tid) * 2];
    rq[tid] = pst[(c * 256 + tid) * 2 + 1];
    __syncthreads();
    for (int off = 128; off > 0; off >>= 1) {
        if (tid < off) { rs[tid] += rs[tid + off]; rq[tid] += rq[tid + off]; }
        __syncthreads();
    }
    if (tid == 0) {
        float mean = rs[0] * invcnt;
        float var = rq[0] * invcnt - mean * mean;
        float sc = g[c] * rsqrtf(var + 1e-4f);
        stats[2 * c] = sc;
        stats[2 * c + 1] = be[c] - mean * sc;
    }
}

__global__ void k_bn_act(const float* __restrict__ x, const float* __restrict__ stats,
                         float* __restrict__ out, int shift, float slope) {
    size_t i = (size_t)blockIdx.x * 256 + threadIdx.x;
    int c = (int)((i >> shift) & 63);
    float sc = stats[2 * c], sh = stats[2 * c + 1];
    float4 v = ((const float4*)x)[i];
    v.x = v.x * sc + sh; v.y = v.y * sc + sh; v.z = v.z * sc + sh; v.w = v.w * sc + sh;
    v.x = v.x > 0 ? v.x : slope * v.x;
    v.y = v.y > 0 ? v.y : slope * v.y;
    v.z = v.z > 0 ? v.z : slope * v.z;
    v.w = v.w > 0 ? v.w : slope * v.w;
    ((float4*)out)[i] = v;
}

// ---------------- devoxelize (bf16 grid), BN(from accs)+lrelu fused ----------------
__global__ void k_devox2(const ushort_t* __restrict__ gcl, const float* __restrict__ accs,
                         const float* __restrict__ g, const float* __restrict__ be,
                         float invcnt, const float* __restrict__ nc,
                         float* __restrict__ out) {
    int b = blockIdx.y;
    int tid = threadIdx.x, p = tid >> 4, q = tid & 15;
    int n = blockIdx.x * 16 + p;
    float x = nc[((size_t)b * 3 + 0) * NN + n];
    float y = nc[((size_t)b * 3 + 1) * NN + n];
    float z = nc[((size_t)b * 3 + 2) * NN + n];
    float fx = floorf(x), fy = floorf(y), fz = floorf(z);
    int lx = (int)fx, ly = (int)fy, lz = (int)fz;
    int hx = min(lx + 1, RR - 1), hy = min(ly + 1, RR - 1), hz = min(lz + 1, RR - 1);
    float frx = x - fx, fry = y - fy, frz = z - fz;
    int xx[2] = {lx, hx}, yy[2] = {ly, hy}, zz[2] = {lz, hz};
    float wx[2] = {1.0f - frx, frx}, wy[2] = {1.0f - fry, fry}, wz[2] = {1.0f - frz, frz};
    float sc[4], sh[4];
    #pragma unroll
    for (int j = 0; j < 4; j++) {
        int c = q * 4 + j;
        float mean = accs[2 * c] * invcnt;
        float var = accs[2 * c + 1] * invcnt - mean * mean;
        float scale = g[c] * rsqrtf(var + 1e-4f);
        sc[j] = scale;
        sh[j] = be[c] - mean * scale;
    }
    float a0 = 0, a1 = 0, a2 = 0, a3 = 0;
    #pragma unroll
    for (int dx = 0; dx < 2; dx++)
        #pragma unroll
        for (int dy = 0; dy < 2; dy++)
            #pragma unroll
            for (int dz = 0; dz < 2; dz++) {
                int idx = (xx[dx] * RR + yy[dy]) * RR + zz[dz];
                float wt = wx[dx] * wy[dy] * wz[dz];
                uint2 pv = *(const uint2*)&gcl[((size_t)b * R3 + idx) * 64 + q * 4];
                float v0 = bf2f((unsigned short)(pv.x & 0xFFFF));
                float v1 = bf2f((unsigned short)(pv.x >> 16));
                float v2 = bf2f((unsigned short)(pv.y & 0xFFFF));
                float v3 = bf2f((unsigned short)(pv.y >> 16));
                float u0 = v0 * sc[0] + sh[0]; u0 = u0 > 0 ? u0 : 0.1f * u0;
                float u1 = v1 * sc[1] + sh[1]; u1 = u1 > 0 ? u1 : 0.1f * u1;
                float u2 = v2 * sc[2] + sh[2]; u2 = u2 > 0 ? u2 : 0.1f * u2;
                float u3 = v3 * sc[3] + sh[3]; u3 = u3 > 0 ? u3 : 0.1f * u3;
                a0 += wt * u0; a1 += wt * u1; a2 += wt * u2; a3 += wt * u3;
            }
    out[((size_t)(b * 64 + q * 4 + 0)) * NN + n] = a0;
    out[((size_t)(b * 64 + q * 4 + 1)) * NN + n] = a1;
    out[((size_t)(b * 64 + q * 4 + 2)) * NN + n] = a2;
    out[((size_t)(b * 64 + q * 4 + 3)) * NN + n] = a3;
}

// ---------------- fuzzy attention (MFMA): ring-4 A staging, counted vmcnt ----------------
// Single barrier per iteration: the top-of-loop barrier (after each lane's own
// t-load retirement via vmcnt(2)) also guarantees no wave can overwrite la[(t+3)&3]
// (== buffer read at t-1) before all waves finished t-1's reads.
__global__ __launch_bounds__(256) void k_fuzzym(const float* __restrict__ coords,
                                                const ushort_t* __restrict__ featb,
                                                float* __restrict__ pnum,
                                                float* __restrict__ pden) {
    __shared__ float cm[3][1024];
    __shared__ ushort_t la[4][2048];
    int b = blockIdx.z, mc = blockIdx.y, nt = blockIdx.x;
    int tid = threadIdx.x;
    int w = tid >> 6, lane = tid & 63, l15 = lane & 15, l4 = lane >> 4;
    int m0 = mc * 1024;

    for (int i = tid; i < 1024; i += 256) {
        float a0 = coords[((size_t)b * 3 + 0) * NN + m0 + i];
        float a1 = coords[((size_t)b * 3 + 1) * NN + m0 + i];
        float a2 = coords[((size_t)b * 3 + 2) * NN + m0 + i];
        float inv = 1.0f / fmaxf(sqrtf(a0 * a0 + a1 * a1 + a2 * a2), 1e-12f);
        cm[0][i] = a0 * inv; cm[1][i] = a1 * inv; cm[2][i] = a2 * inv;
    }

    int n = nt * 64 + w * 16 + l15;
    float q0 = coords[((size_t)b * 3 + 0) * NN + n];
    float q1 = coords[((size_t)b * 3 + 1) * NN + n];
    float q2 = coords[((size_t)b * 3 + 2) * NN + n];
    float qi = 10.0f / fmaxf(sqrtf(q0 * q0 + q1 * q1 + q2 * q2), 1e-12f);
    q0 *= qi; q1 *= qi; q2 *= qi;

    int srow = tid >> 2, sslot = tid & 3;
    int g0 = sslot ^ ((srow >> 1) & 3);
    const ushort_t* fb = featb + (size_t)b * 64 * NN + m0;
    const ushort_t* sbase = fb + (size_t)srow * NN + g0 * 8;
    int rsw = (l15 >> 1) & 3;

    v4f acc[4];
    #pragma unroll
    for (int cb = 0; cb < 4; cb++) acc[cb] = (v4f){0.0f, 0.0f, 0.0f, 0.0f};
    float den = 0.0f;

    gll16(sbase, &la[0][(size_t)tid * 8]);
    gll16(sbase + 32, &la[1][(size_t)tid * 8]);
    gll16(sbase + 64, &la[2][(size_t)tid * 8]);

    for (int t = 0; t < 32; t++) {
        int cur = t & 3;
        asm volatile("s_waitcnt vmcnt(2)" ::: "memory");
        __syncthreads();   // all waves: t-load retired AND t-1 compute done
        if (t + 3 < 32)
            gll16(sbase + (t + 3) * 32, &la[(t + 3) & 3][(size_t)tid * 8]);

        int mo = t * 32 + l4 * 8;
        float e[8];
        #pragma unroll
        for (int jj = 0; jj < 2; jj++) {
            float4 x0 = *(const float4*)&cm[0][mo + jj * 4];
            float4 x1 = *(const float4*)&cm[1][mo + jj * 4];
            float4 x2 = *(const float4*)&cm[2][mo + jj * 4];
            e[jj * 4 + 0] = __expf(q0 * x0.x + q1 * x1.x + q2 * x2.x);
            e[jj * 4 + 1] = __expf(q0 * x0.y + q1 * x1.y + q2 * x2.y);
            e[jj * 4 + 2] = __expf(q0 * x0.z + q1 * x1.z + q2 * x2.z);
            e[jj * 4 + 3] = __expf(q0 * x0.w + q1 * x1.w + q2 * x2.w);
        }
        den += ((e[0] + e[1]) + (e[2] + e[3])) + ((e[4] + e[5]) + (e[6] + e[7]));
        union { __hip_bfloat162 h[4]; v8s v; } pk;
        pk.h[0] = __float22bfloat162_rn(make_float2(e[0], e[1]));
        pk.h[1] = __float22bfloat162_rn(make_float2(e[2], e[3]));
        pk.h[2] = __float22bfloat162_rn(make_float2(e[4], e[5]));
        pk.h[3] = __float22bfloat162_rn(make_float2(e[6], e[7]));
        #pragma unroll
        for (int cb = 0; cb < 4; cb++) {
            v8s A = *(const v8s*)&la[cur][(size_t)((cb * 16 + l15) * 4 + (l4 ^ rsw)) * 8];
            acc[cb] = __builtin_amdgcn_mfma_f32_16x16x32_bf16(A, pk.v, acc[cb], 0, 0, 0);
        }
    }

    den += __shfl_xor(den, 16);
    den += __shfl_xor(den, 32);

    size_t obase = ((size_t)(b * 4 + mc)) * 64 * NN;
    #pragma unroll
    for (int cb = 0; cb < 4; cb++)
        #pragma unroll
        for (int r = 0; r < 4; r++)
            pnum[obase + (size_t)(cb * 16 + l4 * 4 + r) * NN + n] = acc[cb][r];
    if (l4 == 0) pden[((size_t)(b * 4 + mc)) * NN + n] = den;
}

__global__ void k_combine2(const float* __restrict__ pnum, const float* __restrict__ pden,
                           float* __restrict__ fzf) {
    int i = blockIdx.x * 256 + threadIdx.x;
    int b = i >> 18, c = (i >> 12) & 63, n = i & 4095;
    float num = 0, den = 0;
    #pragma unroll
    for (int ch = 0; ch < 4; ch++) {
        num += pnum[((size_t)(b * 4 + ch) * 64 + c) * NN + n];
        den += pden[((size_t)(b * 4 + ch)) * NN + n];
    }
    fzf[((size_t)(b * 64 + c)) * NN + n] = num / den;
}

// ---------------- 1x1 convs: thread = 4n x 1o, partial stats ----------------
__global__ __launch_bounds__(256) void k_1x1s(const float* __restrict__ in,
                                              const float* __restrict__ wT,
                                              const float* __restrict__ bias,
                                              float* __restrict__ out,
                                              float* __restrict__ pst) {
    int b = blockIdx.z, ob = blockIdx.y, bx = blockIdx.x;
    int tid = threadIdx.x;
    int q = tid & 15, o = ob * 16 + (tid >> 4);
    int n = bx * 64 + q * 4;
    const float* src = in + (size_t)b * 64 * NN + n;
    const float* wp_ = wT + o;
    v4f acc = {0, 0, 0, 0};
    #pragma unroll 8
    for (int c = 0; c < 64; c++) {
        float4 x = *(const float4*)&src[(size_t)c * NN];
        float w = wp_[c * 64];
        acc[0] += x.x * w; acc[1] += x.y * w; acc[2] += x.z * w; acc[3] += x.w * w;
    }
    float bv = bias[o];
    float s = 0, q2 = 0;
    float4 ov;
    float* op = (float*)&ov;
    #pragma unroll
    for (int v = 0; v < 4; v++) {
        float val = acc[v] + bv;
        op[v] = val;
        s += val; q2 += val * val;
    }
    *(float4*)&out[((size_t)(b * 64 + o)) * NN + n] = ov;
    #pragma unroll
    for (int off = 1; off < 16; off <<= 1) {
        s += __shfl_xor(s, off);
        q2 += __shfl_xor(q2, off);
    }
    if (q == 0) {
        int part = bx * 4 + b;
        pst[(o * 256 + part) * 2] = s;
        pst[(o * 256 + part) * 2 + 1] = q2;
    }
}

// fusion: segA=vox, segB=pt(BN+relu on the fly), segC=fzf (pre-combined)
__global__ __launch_bounds__(256) void k_1x1f(const float* __restrict__ vox,
                                              const float* __restrict__ pt,
                                              const float* __restrict__ fzf,
                                              const float* __restrict__ bnB,
                                              const float* __restrict__ wfuT,
                                              const float* __restrict__ bC,
                                              float* __restrict__ out,
                                              float* __restrict__ pst) {
    int b = blockIdx.z, ob = blockIdx.y, bx = blockIdx.x;
    int tid = threadIdx.x;
    int q = tid & 15, o = ob * 16 + (tid >> 4);
    int n = bx * 64 + q * 4;
    const float* srcA = vox + (size_t)b * 64 * NN + n;
    const float* srcB = pt + (size_t)b * 64 * NN + n;
    const float* srcC = fzf + (size_t)b * 64 * NN + n;
    const float* wA = wfuT + o;
    v4f acc = {0, 0, 0, 0};
    #pragma unroll 8
    for (int c = 0; c < 64; c++) {
        float4 x = *(const float4*)&srcA[(size_t)c * NN];
        float w = wA[c * 64];
        acc[0] += x.x * w; acc[1] += x.y * w; acc[2] += x.z * w; acc[3] += x.w * w;
    }
    #pragma unroll 8
    for (int c = 0; c < 64; c++) {
        float4 x = *(const float4*)&srcB[(size_t)c * NN];
        float sc = bnB[2 * c], sh = bnB[2 * c + 1];
        float w = wA[(64 + c) * 64];
        float x0 = fmaxf(x.x * sc + sh, 0.0f), x1 = fmaxf(x.y * sc + sh, 0.0f);
        float x2 = fmaxf(x.z * sc + sh, 0.0f), x3 = fmaxf(x.w * sc + sh, 0.0f);
        acc[0] += x0 * w; acc[1] += x1 * w; acc[2] += x2 * w; acc[3] += x3 * w;
    }
    #pragma unroll 8
    for (int c = 0; c < 64; c++) {
        float4 x = *(const float4*)&srcC[(size_t)c * NN];
        float w = wA[(128 + c) * 64];
        acc[0] += x.x * w; acc[1] += x.y * w; acc[2] += x.z * w; acc[3] += x.w * w;
    }
    float bv = bC[o];
    float s = 0, q2 = 0;
    float4 ov;
    float* op = (float*)&ov;
    #pragma unroll
    for (int v = 0; v < 4; v++) {
        float val = acc[v] + bv;
        op[v] = val;
        s += val; q2 += val * val;
    }
    *(float4*)&out[((size_t)(b * 64 + o)) * NN + n] = ov;
    #pragma unroll
    for (int off = 1; off < 16; off <<= 1) {
        s += __shfl_xor(s, off);
        q2 += __shfl_xor(q2, off);
    }
    if (q == 0) {
        int part = bx * 4 + b;
        pst[(o * 256 + part) * 2] = s;
        pst[(o * 256 + part) * 2 + 1] = q2;
    }
}

// ---------------- launcher ----------------
extern "C" void kernel_launch(void* const* d_in, const int* in_sizes, int n_in,
                              void* d_out, int out_size, void* d_ws, size_t ws_size,
                              hipStream_t stream) {
    const float* features = (const float*)d_in[0];
    const float* coords = (const float*)d_in[1];
    const float* w1 = (const float*)d_in[2];
    const float* g1 = (const float*)d_in[4];
    const float* be1 = (const float*)d_in[5];
    const float* w2 = (const float*)d_in[6];
    const float* g2 = (const float*)d_in[8];
    const float* be2 = (const float*)d_in[9];
    const float* wp = (const float*)d_in[10];
    const float* bp = (const float*)d_in[11];
    const float* gp = (const float*)d_in[12];
    const float* bep = (const float*)d_in[13];
    const float* wf = (const float*)d_in[14];
    const float* bf = (const float*)d_in[15];
    const float* wfu = (const float*)d_in[16];
    const float* bfu = (const float*)d_in[17];
    const float* gfu = (const float*)d_in[18];
    const float* befu = (const float*)d_in[19];

    float* ws = (float*)d_ws;
    float* nc = ws;                        // 49152
    int* vidx = (int*)(ws + 49152);        // 16384 ints
    int* cntI = (int*)(ws + 65536);        // 131072 ints (pden overlays later)
    float* pden = ws + 65536;
    float* gridCL = ws + 196608;           // conv outputs (bf16 raw both convs)
    ushort_t* gTraw = (ushort_t*)gridCL;
    int* rank = (int*)(ws + 196608);       // overlay (pre-conv only)
    int* lscan = (int*)(ws + 327680);
    int* bsum = (int*)(ws + 458752);
    int* bbase = (int*)(ws + 459264);
    int* plist = (int*)(ws + 459776);
    float* featT = ws + 476160;            // 1048576 floats
    float* gTpool = ws + 8585216;          // gT bf16 / pnum / pstB
    ushort_t* gT = (ushort_t*)gTpool;
    float* pnum = gTpool;                  // 4,194,304 floats
    float* pstB = gTpool + 4194304;        // 32768 floats (disjoint from pnum)
    float* stats = ws + 16973824;
    float* voxreg = ws + 16974336;
    ushort_t* wS1 = (ushort_t*)voxreg;
    ushort_t* wS2 = wS1 + 110592;
    float* vox = voxreg;
    float* pt = ws + 18022912;
    float* fzf = ws + 19071488;
    float* wpT = ws + 20120064;
    float* wfuT = wpT + 4096;
    float* bC = wfuT + 12288;
    float* fpre = ws + 21168640;
    ushort_t* featb = (ushort_t*)fpre;
    float* accs = ws + 22217216;

    float* out = (float*)d_out;

    hipMemsetAsync(cntI, 0, (size_t)131072 * 4, stream);
    hipMemsetAsync(rank, 0, (size_t)131072 * 4, stream);

    // prep (independent); k_fold also zeroes accs
    k_fold<<<67, 256, 0, stream>>>(wp, wfu, wf, bf, bfu, wpT, wfuT, bC, accs);
    k_pfeat<<<dim3(64, BB), 256, 0, stream>>>(features, featT, featb);
    k_tws<<<864, 256, 0, stream>>>(w1, w2, wS1, wS2);

    // voxelization: CSR gather-mean
    k_nc<<<BB, 256, 0, stream>>>(coords, nc, vidx, cntI);
    k_scan1<<<512, 256, 0, stream>>>(cntI, lscan, bsum);
    k_scan2<<<1, 512, 0, stream>>>(bsum, bbase);
    k_fill<<<BB * NN / 256, 256, 0, stream>>>(vidx, lscan, bbase, rank, plist);
    k_gather<<<4096, 256, 0, stream>>>(featT, cntI, lscan, bbase, plist, gT);

    // voxel branch (both convs bf16-out; R19 proven 512-block 8-row tiles)
    k_convlds<1><<<512, 256, 0, stream>>>(gT, wS1, gTraw, accs);
    k_bncast2<<<BB * R3 * 64 / 8 / 256, 256, 0, stream>>>(gTraw, accs, g1, be1,
                                                          1.0f / (BB * R3), 0.1f, gT);
    k_convlds<1><<<512, 256, 0, stream>>>(gT, wS2, gTraw, accs + 128);
    k_devox2<<<dim3(NN / 16, BB), 256, 0, stream>>>(gTraw, accs + 128, g2, be2,
                                                    1.0f / (BB * R3), nc, vox);

    // fuzzy branch
    k_fuzzym<<<dim3(64, 4, BB), 256, 0, stream>>>(coords, featb, pnum, pden);
    k_combine2<<<BB * 64 * NN / 256, 256, 0, stream>>>(pnum, pden, fzf);

    // point branch
    k_1x1s<<<dim3(NN / 64, 4, BB), 256, 0, stream>>>(features, wpT, bp, pt, pstB);
    k_bnfin2<<<64, 256, 0, stream>>>(pstB, gp, bep, stats + 256, 1.0f / (BB * NN));

    // fusion
    k_1x1f<<<dim3(NN / 64, 4, BB), 256, 0, stream>>>(vox, pt, fzf, stats + 256, wfuT, bC,
                                                     fpre, pstB);
    k_bnfin2<<<64, 256, 0, stream>>>(pstB, gfu, befu, stats + 384, 1.0f / (BB * NN));
    k_bn_act<<<BB * 64 * NN / 4 / 256, 256, 0, stream>>>(fpre, stats + 384, out, 10, 0.0f);

    hipMemcpyAsync(out + (size_t)BB * CO * NN, coords, (size_t)BB * 3 * NN * 4,
                   hipMemcpyDeviceToDevice, stream);
}

// Round 22
// 256.630 us; speedup vs baseline: 1.1341x; 1.0519x over previous
//
#include <hip/hip_runtime.h>
#include <hip/hip_bf16.h>
#include <math.h>

#define RR 32
#define R3 32768
#define BB 4
#define CI 64
#define CO 64
#define NN 4096

typedef short v8s __attribute__((ext_vector_type(8)));
typedef float v4f __attribute__((ext_vector_type(4)));
typedef unsigned short ushort_t;

__device__ __forceinline__ unsigned short f2bf(float f) {
    unsigned int u = __float_as_uint(f);
    unsigned int r = (u + 0x7FFFu + ((u >> 16) & 1u)) >> 16;
    return (unsigned short)r;
}
__device__ __forceinline__ float bf2f(unsigned short h) {
    return __uint_as_float((unsigned int)h << 16);
}

__device__ __forceinline__ void gll16(const void* g, void* l) {
    __builtin_amdgcn_global_load_lds((const __attribute__((address_space(1))) unsigned int*)g,
                                     (__attribute__((address_space(3))) unsigned int*)l, 16, 0, 0);
}

// ---------------- block reduce helpers ----------------
__device__ __forceinline__ float blockReduceSum(float v, float* sm) {
    int tid = threadIdx.x;
    sm[tid] = v; __syncthreads();
    for (int off = 128; off > 0; off >>= 1) {
        if (tid < off) sm[tid] += sm[tid + off];
        __syncthreads();
    }
    float r = sm[0]; __syncthreads();
    return r;
}
__device__ __forceinline__ float blockReduceMax(float v, float* sm) {
    int tid = threadIdx.x;
    sm[tid] = v; __syncthreads();
    for (int off = 128; off > 0; off >>= 1) {
        if (tid < off) sm[tid] = fmaxf(sm[tid], sm[tid + off]);
        __syncthreads();
    }
    float r = sm[0]; __syncthreads();
    return r;
}

// ---------------- prep megakernel: fold + tws + pfeat + cntI zero ----------------
// blocks [0,67): weight fold/transposes + accs zero
// blocks [67,931): conv weight transform (both convs)
// blocks [931,1187): feature transpose (featT) + bf16 cast (featb)
// blocks [1187,1699): zero cntI
__global__ void k_prep(const float* __restrict__ wp, const float* __restrict__ wfu,
                       const float* __restrict__ wf, const float* __restrict__ bf,
                       const float* __restrict__ bfu,
                       float* __restrict__ wpT, float* __restrict__ wfuT,
                       float* __restrict__ bC, float* __restrict__ accs,
                       const float* __restrict__ w1, const float* __restrict__ w2,
                       ushort_t* __restrict__ wS1, ushort_t* __restrict__ wS2,
                       const float* __restrict__ feat, float* __restrict__ featT,
                       ushort_t* __restrict__ featb, int* __restrict__ cntI) {
    __shared__ float t[64][65];
    int bid = blockIdx.x, tid = threadIdx.x;
    if (bid < 67) {
        int i = bid * 256 + tid;
        if (i < 4096) {
            int c = i >> 6, o = i & 63;
            wpT[c * 64 + o] = wp[o * 64 + c];
        } else if (i < 12288) {
            int j = i - 4096;
            int c = j >> 6, o = j & 63;
            wfuT[c * 64 + o] = wfu[(size_t)o * 192 + c];
        } else if (i < 16384) {
            int j = i - 12288;
            int c = j >> 6, o = j & 63;
            float s = 0;
            for (int k = 0; k < 64; k++)
                s += wfu[(size_t)o * 192 + 128 + k] * wf[(size_t)k * 64 + c];
            wfuT[(128 + c) * 64 + o] = s;
        } else if (i < 16448) {
            int o = i - 16384;
            float s = bfu[o];
            for (int k = 0; k < 64; k++)
                s += wfu[(size_t)o * 192 + 128 + k] * bf[k];
            bC[o] = s;
        } else if (i < 16960) {
            accs[i - 16448] = 0.0f;
        }
    } else if (bid < 931) {
        int i = (bid - 67) * 256 + tid;  // 221184
        const float* w = (i < 110592) ? w1 : w2;
        ushort_t* wS = (i < 110592) ? wS1 : wS2;
        int j = (i < 110592) ? i : i - 110592;
        int cis = j & 31, co = (j >> 5) & 63;
        int dx = (j >> 11) % 3, cih = (j / 6144) & 1, dzdy = j / 12288;
        int k = dzdy * 3 + dx, ci = cih * 32 + cis;
        wS[j] = f2bf(w[((size_t)co * CI + ci) * 27 + k]);
    } else if (bid < 1187) {
        int pb = bid - 931;
        int b = pb >> 6, n0 = (pb & 63) * 64;
        int q = tid >> 6, nl = tid & 63;
        #pragma unroll
        for (int k = 0; k < 16; k++) {
            int c = q * 16 + k;
            float v = feat[((size_t)(b * CI + c)) * NN + n0 + nl];
            t[nl][c] = v;
            featb[((size_t)(b * CI + c)) * NN + n0 + nl] = f2bf(v);
        }
        __syncthreads();
        #pragma unroll
        for (int k = 0; k < 16; k++) {
            int n = q * 16 + k;
            featT[((size_t)b * NN + n0 + n) * 64 + nl] = t[n][nl];
        }
    } else {
        int z = (bid - 1187) * 256 + tid;  // 131072
        cntI[z] = 0;
    }
}

// ---------------- voxel coords + fused voxel count ----------------
__global__ void k_nc(const float* __restrict__ coords, float* __restrict__ nc,
                     int* __restrict__ vidx, int* __restrict__ cntI) {
    int b = blockIdx.x, tid = threadIdx.x;
    __shared__ float sm[256];
    const float* cb = coords + (size_t)b * 3 * NN;
    float s0 = 0, s1 = 0, s2 = 0;
    for (int n = tid; n < NN; n += 256) {
        s0 += cb[n]; s1 += cb[NN + n]; s2 += cb[2 * NN + n];
    }
    float m0 = blockReduceSum(s0, sm) * (1.0f / NN);
    float m1 = blockReduceSum(s1, sm) * (1.0f / NN);
    float m2 = blockReduceSum(s2, sm) * (1.0f / NN);
    float mx = 0;
    for (int n = tid; n < NN; n += 256) {
        float dx = cb[n] - m0, dy = cb[NN + n] - m1, dz = cb[2 * NN + n] - m2;
        mx = fmaxf(mx, dx * dx + dy * dy + dz * dz);
    }
    mx = blockReduceMax(mx, sm);
    float denom = 2.0f * sqrtf(mx);
    float mean[3] = {m0, m1, m2};
    for (int n = tid; n < NN; n += 256) {
        int vi[3];
        #pragma unroll
        for (int ax = 0; ax < 3; ax++) {
            float x = (cb[ax * NN + n] - mean[ax]) / denom + 0.5f;
            x = x * RR;
            x = fminf(fmaxf(x, 0.0f), (float)(RR - 1));
            nc[((size_t)b * 3 + ax) * NN + n] = x;
            vi[ax] = (int)rintf(x);
        }
        int idx = (vi[0] * RR + vi[1]) * RR + vi[2];
        vidx[b * NN + n] = idx;
        atomicAdd(&cntI[b * R3 + idx], 1);
    }
}

// ---------------- scan (also zeroes rank) ----------------
__global__ void k_scan1(const int* __restrict__ cntI, int* __restrict__ lscan,
                        int* __restrict__ bsum, int* __restrict__ rank) {
    __shared__ int sm[256];
    int tid = threadIdx.x;
    int i = blockIdx.x * 256 + tid;
    rank[i] = 0;
    int v = cntI[i];
    sm[tid] = v; __syncthreads();
    for (int off = 1; off < 256; off <<= 1) {
        int t = (tid >= off) ? sm[tid - off] : 0;
        __syncthreads();
        sm[tid] += t;
        __syncthreads();
    }
    lscan[i] = sm[tid] - v;
    if (tid == 255) bsum[blockIdx.x] = sm[tid];
}

__global__ void k_scan2(const int* __restrict__ bsum, int* __restrict__ bbase) {
    __shared__ int sm[512];
    int tid = threadIdx.x;
    int v = bsum[tid];
    sm[tid] = v; __syncthreads();
    for (int off = 1; off < 512; off <<= 1) {
        int t = (tid >= off) ? sm[tid - off] : 0;
        __syncthreads();
        sm[tid] += t;
        __syncthreads();
    }
    bbase[tid] = sm[tid] - v;
}

// ---------------- fill CSR point lists ----------------
__global__ void k_fill(const int* __restrict__ vidx, const int* __restrict__ lscan,
                       const int* __restrict__ bbase, int* __restrict__ rank,
                       int* __restrict__ plist) {
    int i = blockIdx.x * 256 + threadIdx.x;  // B*NN
    int b = i >> 12, n = i & (NN - 1);
    int flat = b * R3 + vidx[i];
    int r = atomicAdd(&rank[flat], 1);
    plist[bbase[flat >> 8] + lscan[flat] + r] = n;
}

// ---------------- segmented gather-mean -> gT bf16 cl ----------------
__global__ __launch_bounds__(256) void k_gather(const float* __restrict__ featT,
                                                const int* __restrict__ cntI,
                                                const int* __restrict__ lscan,
                                                const int* __restrict__ bbase,
                                                const int* __restrict__ plist,
                                                ushort_t* __restrict__ gT) {
    int wv = threadIdx.x >> 6, lane = threadIdx.x & 63;
    int vbase = blockIdx.x * 32 + wv * 8;
    for (int k = 0; k < 8; k++) {
        int flat = vbase + k;
        int count = cntI[flat];
        float s = 0.0f;
        if (count > 0) {
            int b = flat >> 15;
            int start = bbase[flat >> 8] + lscan[flat];
            for (int j = 0; j < count; j++) {
                int n = plist[start + j];
                s += featT[((size_t)b * NN + n) * 64 + lane];
            }
            s *= 1.0f / (float)count;
        }
        gT[(size_t)flat * 64 + lane] = f2bf(s);
    }
}

// ---------------- BN(from accs) + lrelu, bf16 -> bf16 (cl -> cl) ----------------
__global__ void k_bncast2(const ushort_t* __restrict__ x, const float* __restrict__ accs,
                          const float* __restrict__ g, const float* __restrict__ be,
                          float invcnt, float slope, ushort_t* __restrict__ o) {
    size_t i = (size_t)blockIdx.x * 256 + threadIdx.x;  // over B*R3*64/8
    int c0 = (int)((i * 8) & 63);
    float sc[8], sh[8];
    #pragma unroll
    for (int j = 0; j < 8; j++) {
        int c = c0 + j;
        float mean = accs[2 * c] * invcnt;
        float var = accs[2 * c + 1] * invcnt - mean * mean;
        float scale = g[c] * rsqrtf(var + 1e-4f);
        sc[j] = scale;
        sh[j] = be[c] - mean * scale;
    }
    uint4 in = ((const uint4*)x)[i];
    unsigned iv[4] = {in.x, in.y, in.z, in.w};
    unsigned pk[4];
    #pragma unroll
    for (int j = 0; j < 4; j++) {
        float u0 = bf2f((unsigned short)(iv[j] & 0xFFFF)) * sc[2 * j] + sh[2 * j];
        float u1 = bf2f((unsigned short)(iv[j] >> 16)) * sc[2 * j + 1] + sh[2 * j + 1];
        u0 = u0 > 0 ? u0 : slope * u0;
        u1 = u1 > 0 ? u1 : slope * u1;
        pk[j] = (unsigned)f2bf(u0) | ((unsigned)f2bf(u1) << 16);
    }
    ((uint4*)o)[i] = make_uint4(pk[0], pk[1], pk[2], pk[3]);
}

// ---------------- LDS-staged MFMA conv3d 3x3x3 (R19 proven config) ----------------
template <int OUTBF16>
__global__ __launch_bounds__(256) void k_convlds(const ushort_t* __restrict__ gT,
                                                 const ushort_t* __restrict__ wS,
                                                 void* __restrict__ outP,
                                                 float* __restrict__ accs) {
    __shared__ ushort_t lin[20480];     // 40960B input plane (sbuf overlays: 33792B <= 40960B)
    __shared__ ushort_t lw[2][6144];    // 2 x 12288B weights
    int bid = blockIdx.x;
    int wgid = (bid & 7) * 64 + (bid >> 3);
    int yt = wgid & 3, z0 = (wgid >> 2) & 31, b = wgid >> 7;
    int tid = threadIdx.x;
    int w = __builtin_amdgcn_readfirstlane(tid >> 6);
    int lane = tid & 63, l15 = lane & 15, l4 = lane >> 4;
    int y0 = yt * 8;
    const ushort_t* gTb = gT + (size_t)b * R3 * 64;

    int voxF[4];
    #pragma unroll
    for (int f = 0; f < 4; f++)
        voxF[f] = (w * 2 + (f >> 1)) * 32 + (f & 1) * 16 + l15 - 1;
    bool xlo_ok = (l15 != 0), xhi_ok = (l15 != 15);

    int lsw = lane ^ ((lane >> 3) & 7);
    int wsz8 = ((l15 * 4 + l4) ^ ((l15 >> 1) & 7)) * 8;

    const v8s vzero = {};
    v4f acc[4][4];
    #pragma unroll
    for (int m = 0; m < 4; m++)
        #pragma unroll
        for (int f = 0; f < 4; f++)
            acc[m][f] = (v4f){0.0f, 0.0f, 0.0f, 0.0f};

#define WSTAGE(s)                                                              \
    do {                                                                       \
        const ushort_t* _src = wS + (size_t)(s) * 6144;                        \
        ushort_t* _dst = lw[(s) & 1];                                          \
        _Pragma("unroll") for (int _i = 0; _i < 3; _i++) {                     \
            int _pb = _i * 256 + w * 64;                                       \
            gll16(_src + (size_t)(_pb + lsw) * 8, _dst + (size_t)(_pb + lane) * 8); \
        }                                                                      \
    } while (0)

#define ISTAGE(dz)                                                             \
    do {                                                                       \
        int _zp = z0 - 1 + (dz);                                               \
        if (_zp < 0 || _zp > 31) {                                             \
            for (int _q = 0; _q < 10; _q++)                                    \
                *(v8s*)&lin[(size_t)(w * 640 + _q * 64 + lane) * 8] = vzero;   \
        } else {                                                               \
            if (yt == 0) *(v8s*)&lin[(size_t)tid * 8] = vzero;                 \
            if (yt == 3) *(v8s*)&lin[(size_t)(2304 + tid) * 8] = vzero;        \
            const ushort_t* _pb = gTb + ((size_t)_zp * 1024 + (size_t)(y0 - 1) * 32) * 64; \
            int _g0 = (yt == 0) ? 256 : 0;                                     \
            int _nc = 10 - (yt == 0) - (yt == 3);                              \
            for (int _i = 0; _i < _nc; _i++) {                                 \
                int _pbase = _g0 + _i * 256 + w * 64;                          \
                int _p = _pbase + lane;                                        \
                int _vx = _p >> 3, _js = _p & 7;                               \
                int _sg = _vx * 8 + (_js ^ (_vx & 7));                         \
                gll16(_pb + (size_t)_sg * 8, lin + (size_t)_pbase * 8);        \
            }                                                                  \
        }                                                                      \
    } while (0)

    WSTAGE(0);
    for (int s = 0; s < 18; s++) {
        int dy = (s / 2) % 3, cih = s & 1;
        asm volatile("s_barrier" ::: "memory");
        if ((s % 6) == 0) ISTAGE(s / 6);
        if (s + 1 < 18) WSTAGE(s + 1);
        if (s + 1 < 18) asm volatile("s_waitcnt vmcnt(3) lgkmcnt(0)" ::: "memory");
        else            asm volatile("s_waitcnt vmcnt(0) lgkmcnt(0)" ::: "memory");
        asm volatile("s_barrier" ::: "memory");

        const ushort_t* lwb = lw[s & 1];
        #pragma unroll
        for (int dx = 0; dx < 3; dx++) {
            v8s Bf[4];
            #pragma unroll
            for (int f = 0; f < 4; f++) {
                int vox = voxF[f] + dy * 32 + dx;
                int g = vox * 8 + ((cih * 4 + l4) ^ (vox & 7));
                int bix = g * 16;
                bix = bix < 0 ? 0 : bix;
                v8s vb = *(const v8s*)((const char*)lin + bix);
                bool ok = (dx == 0 && (f & 1) == 0) ? xlo_ok :
                          (dx == 2 && (f & 1) == 1) ? xhi_ok : true;
                Bf[f] = ok ? vb : vzero;
            }
            const ushort_t* ap = lwb + dx * 2048 + wsz8;
            #pragma unroll
            for (int m = 0; m < 4; m++) {
                v8s Af = *(const v8s*)(ap + m * 512);
                #pragma unroll
                for (int f = 0; f < 4; f++)
                    acc[m][f] = __builtin_amdgcn_mfma_f32_16x16x32_bf16(Af, Bf[f], acc[m][f], 0, 0, 0);
            }
        }
    }

    // stores
    #pragma unroll
    for (int m = 0; m < 4; m++) {
        #pragma unroll
        for (int f = 0; f < 4; f++) {
            int y = y0 + w * 2 + (f >> 1);
            int x = (f & 1) * 16 + l15;
            size_t base = ((size_t)b * R3 + z0 * 1024 + y * 32 + x) * 64 + m * 16 + l4 * 4;
            if (OUTBF16) {
                unsigned p0 = (unsigned)f2bf(acc[m][f][0]) | ((unsigned)f2bf(acc[m][f][1]) << 16);
                unsigned p1 = (unsigned)f2bf(acc[m][f][2]) | ((unsigned)f2bf(acc[m][f][3]) << 16);
                *(uint2*)&((ushort_t*)outP)[base] = make_uint2(p0, p1);
            } else {
                float4 o = make_float4(acc[m][f][0], acc[m][f][1], acc[m][f][2], acc[m][f][3]);
                *(float4*)&((float*)outP)[base] = o;
            }
        }
    }

    // fused BN-stats (sbuf overlays lin; stride-33: conflict-free)
    __syncthreads();
    float* sbuf = (float*)lin;
    #pragma unroll
    for (int m = 0; m < 4; m++)
        #pragma unroll
        for (int r = 0; r < 4; r++) {
            float s = 0, q = 0;
            #pragma unroll
            for (int f = 0; f < 4; f++) {
                float v = acc[m][f][r];
                s += v; q += v * v;
            }
            sbuf[tid * 33 + (m * 4 + r) * 2] = s;
            sbuf[tid * 33 + (m * 4 + r) * 2 + 1] = q;
        }
    __syncthreads();
    if (tid < 128) {
        int co = tid >> 1, val = tid & 1;
        int m = co >> 4, cl4 = (co >> 2) & 3, r = co & 3;
        float a = 0;
        for (int w2 = 0; w2 < 4; w2++)
            for (int l = 0; l < 16; l++)
                a += sbuf[(w2 * 64 + cl4 * 16 + l) * 33 + (m * 4 + r) * 2 + val];
        atomicAdd(&accs[2 * co + val], a);
    }
#undef WSTAGE
#undef ISTAGE
}

// reduce 256 partials per channel (pt path)
__global__ void k_bnfin2(const float* __restrict__ pst, const float* __restrict__ g,
                         const float* __restrict__ be, float* __restrict__ stats,
                         float invcnt) {
    int c = blockIdx.x, tid = threadIdx.x;
    __shared__ float rs[256], rq[256];
    rs[tid] = pst[(c * 256 + tid) * 2];
    rq[tid] = pst[(c * 256 + tid) * 2 + 1];
    __syncthreads();
    for (int off = 128; off > 0; off >>= 1) {
        if (tid < off) { rs[tid] += rs[tid + off]; rq[tid] += rq[tid + off]; }
        __syncthreads();
    }
    if (tid == 0) {
        float mean = rs[0] * invcnt;
        float var = rq[0] * invcnt - mean * mean;
        float sc = g[c] * rsqrtf(var + 1e-4f);
        stats[2 * c] = sc;
        stats[2 * c + 1] = be[c] - mean * sc;
    }
}

// ---------------- fused BN finalize+apply (fusion output): one channel per block ----------------
__global__ void k_bnact2(const float* __restrict__ x, const float* __restrict__ pst,
                         const float* __restrict__ g, const float* __restrict__ be,
                         float invcnt, float* __restrict__ out) {
    int bid = blockIdx.x, tid = threadIdx.x;
    int c = (bid >> 2) & 63;          // 256 f4/block, 1024 f4 per (b,c) -> c constant in block
    __shared__ float rs[256], rq[256];
    __shared__ float sscale, sshift;
    rs[tid] = pst[(c * 256 + tid) * 2];
    rq[tid] = pst[(c * 256 + tid) * 2 + 1];
    __syncthreads();
    for (int off = 128; off > 0; off >>= 1) {
        if (tid < off) { rs[tid] += rs[tid + off]; rq[tid] += rq[tid + off]; }
        __syncthreads();
    }
    if (tid == 0) {
        float mean = rs[0] * invcnt;
        float var = rq[0] * invcnt - mean * mean;
        float sc = g[c] * rsqrtf(var + 1e-4f);
        sscale = sc;
        sshift = be[c] - mean * sc;
    }
    __syncthreads();
    float sc = sscale, sh = sshift;
    size_t i = (size_t)bid * 256 + tid;
    float4 v = ((const float4*)x)[i];
    v.x = fmaxf(v.x * sc + sh, 0.0f);
    v.y = fmaxf(v.y * sc + sh, 0.0f);
    v.z = fmaxf(v.z * sc + sh, 0.0f);
    v.w = fmaxf(v.w * sc + sh, 0.0f);
    ((float4*)out)[i] = v;
}

// ---------------- devoxelize (bf16 grid), BN(from accs)+lrelu fused ----------------
__global__ void k_devox2(const ushort_t* __restrict__ gcl, const float* __restrict__ accs,
                         const float* __restrict__ g, const float* __restrict__ be,
                         float invcnt, const float* __restrict__ nc,
                         float* __restrict__ out) {
    int b = blockIdx.y;
    int tid = threadIdx.x, p = tid >> 4, q = tid & 15;
    int n = blockIdx.x * 16 + p;
    float x = nc[((size_t)b * 3 + 0) * NN + n];
    float y = nc[((size_t)b * 3 + 1) * NN + n];
    float z = nc[((size_t)b * 3 + 2) * NN + n];
    float fx = floorf(x), fy = floorf(y), fz = floorf(z);
    int lx = (int)fx, ly = (int)fy, lz = (int)fz;
    int hx = min(lx + 1, RR - 1), hy = min(ly + 1, RR - 1), hz = min(lz + 1, RR - 1);
    float frx = x - fx, fry = y - fy, frz = z - fz;
    int xx[2] = {lx, hx}, yy[2] = {ly, hy}, zz[2] = {lz, hz};
    float wx[2] = {1.0f - frx, frx}, wy[2] = {1.0f - fry, fry}, wz[2] = {1.0f - frz, frz};
    float sc[4], sh[4];
    #pragma unroll
    for (int j = 0; j < 4; j++) {
        int c = q * 4 + j;
        float mean = accs[2 * c] * invcnt;
        float var = accs[2 * c + 1] * invcnt - mean * mean;
        float scale = g[c] * rsqrtf(var + 1e-4f);
        sc[j] = scale;
        sh[j] = be[c] - mean * scale;
    }
    float a0 = 0, a1 = 0, a2 = 0, a3 = 0;
    #pragma unroll
    for (int dx = 0; dx < 2; dx++)
        #pragma unroll
        for (int dy = 0; dy < 2; dy++)
            #pragma unroll
            for (int dz = 0; dz < 2; dz++) {
                int idx = (xx[dx] * RR + yy[dy]) * RR + zz[dz];
                float wt = wx[dx] * wy[dy] * wz[dz];
                uint2 pv = *(const uint2*)&gcl[((size_t)b * R3 + idx) * 64 + q * 4];
                float v0 = bf2f((unsigned short)(pv.x & 0xFFFF));
                float v1 = bf2f((unsigned short)(pv.x >> 16));
                float v2 = bf2f((unsigned short)(pv.y & 0xFFFF));
                float v3 = bf2f((unsigned short)(pv.y >> 16));
                float u0 = v0 * sc[0] + sh[0]; u0 = u0 > 0 ? u0 : 0.1f * u0;
                float u1 = v1 * sc[1] + sh[1]; u1 = u1 > 0 ? u1 : 0.1f * u1;
                float u2 = v2 * sc[2] + sh[2]; u2 = u2 > 0 ? u2 : 0.1f * u2;
                float u3 = v3 * sc[3] + sh[3]; u3 = u3 > 0 ? u3 : 0.1f * u3;
                a0 += wt * u0; a1 += wt * u1; a2 += wt * u2; a3 += wt * u3;
            }
    out[((size_t)(b * 64 + q * 4 + 0)) * NN + n] = a0;
    out[((size_t)(b * 64 + q * 4 + 1)) * NN + n] = a1;
    out[((size_t)(b * 64 + q * 4 + 2)) * NN + n] = a2;
    out[((size_t)(b * 64 + q * 4 + 3)) * NN + n] = a3;
}

// ---------------- fuzzy attention (MFMA): ring-4 A staging, counted vmcnt ----------------
__global__ __launch_bounds__(256) void k_fuzzym(const float* __restrict__ coords,
                                                const ushort_t* __restrict__ featb,
                                                float* __restrict__ pnum,
                                                float* __restrict__ pden) {
    __shared__ float cm[3][1024];
    __shared__ ushort_t la[4][2048];
    int b = blockIdx.z, mc = blockIdx.y, nt = blockIdx.x;
    int tid = threadIdx.x;
    int w = tid >> 6, lane = tid & 63, l15 = lane & 15, l4 = lane >> 4;
    int m0 = mc * 1024;

    for (int i = tid; i < 1024; i += 256) {
        float a0 = coords[((size_t)b * 3 + 0) * NN + m0 + i];
        float a1 = coords[((size_t)b * 3 + 1) * NN + m0 + i];
        float a2 = coords[((size_t)b * 3 + 2) * NN + m0 + i];
        float inv = 1.0f / fmaxf(sqrtf(a0 * a0 + a1 * a1 + a2 * a2), 1e-12f);
        cm[0][i] = a0 * inv; cm[1][i] = a1 * inv; cm[2][i] = a2 * inv;
    }

    int n = nt * 64 + w * 16 + l15;
    float q0 = coords[((size_t)b * 3 + 0) * NN + n];
    float q1 = coords[((size_t)b * 3 + 1) * NN + n];
    float q2 = coords[((size_t)b * 3 + 2) * NN + n];
    float qi = 10.0f / fmaxf(sqrtf(q0 * q0 + q1 * q1 + q2 * q2), 1e-12f);
    q0 *= qi; q1 *= qi; q2 *= qi;

    int srow = tid >> 2, sslot = tid & 3;
    int g0 = sslot ^ ((srow >> 1) & 3);
    const ushort_t* fb = featb + (size_t)b * 64 * NN + m0;
    const ushort_t* sbase = fb + (size_t)srow * NN + g0 * 8;
    int rsw = (l15 >> 1) & 3;

    v4f acc[4];
    #pragma unroll
    for (int cb = 0; cb < 4; cb++) acc[cb] = (v4f){0.0f, 0.0f, 0.0f, 0.0f};
    float den = 0.0f;

    gll16(sbase, &la[0][(size_t)tid * 8]);
    gll16(sbase + 32, &la[1][(size_t)tid * 8]);
    gll16(sbase + 64, &la[2][(size_t)tid * 8]);

    for (int t = 0; t < 32; t++) {
        int cur = t & 3;
        asm volatile("s_waitcnt vmcnt(2)" ::: "memory");
        __syncthreads();
        if (t + 3 < 32)
            gll16(sbase + (t + 3) * 32, &la[(t + 3) & 3][(size_t)tid * 8]);

        int mo = t * 32 + l4 * 8;
        float e[8];
        #pragma unroll
        for (int jj = 0; jj < 2; jj++) {
            float4 x0 = *(const float4*)&cm[0][mo + jj * 4];
            float4 x1 = *(const float4*)&cm[1][mo + jj * 4];
            float4 x2 = *(const float4*)&cm[2][mo + jj * 4];
            e[jj * 4 + 0] = __expf(q0 * x0.x + q1 * x1.x + q2 * x2.x);
            e[jj * 4 + 1] = __expf(q0 * x0.y + q1 * x1.y + q2 * x2.y);
            e[jj * 4 + 2] = __expf(q0 * x0.z + q1 * x1.z + q2 * x2.z);
            e[jj * 4 + 3] = __expf(q0 * x0.w + q1 * x1.w + q2 * x2.w);
        }
        den += ((e[0] + e[1]) + (e[2] + e[3])) + ((e[4] + e[5]) + (e[6] + e[7]));
        union { __hip_bfloat162 h[4]; v8s v; } pk;
        pk.h[0] = __float22bfloat162_rn(make_float2(e[0], e[1]));
        pk.h[1] = __float22bfloat162_rn(make_float2(e[2], e[3]));
        pk.h[2] = __float22bfloat162_rn(make_float2(e[4], e[5]));
        pk.h[3] = __float22bfloat162_rn(make_float2(e[6], e[7]));
        #pragma unroll
        for (int cb = 0; cb < 4; cb++) {
            v8s A = *(const v8s*)&la[cur][(size_t)((cb * 16 + l15) * 4 + (l4 ^ rsw)) * 8];
            acc[cb] = __builtin_amdgcn_mfma_f32_16x16x32_bf16(A, pk.v, acc[cb], 0, 0, 0);
        }
    }

    den += __shfl_xor(den, 16);
    den += __shfl_xor(den, 32);

    size_t obase = ((size_t)(b * 4 + mc)) * 64 * NN;
    #pragma unroll
    for (int cb = 0; cb < 4; cb++)
        #pragma unroll
        for (int r = 0; r < 4; r++)
            pnum[obase + (size_t)(cb * 16 + l4 * 4 + r) * NN + n] = acc[cb][r];
    if (l4 == 0) pden[((size_t)(b * 4 + mc)) * NN + n] = den;
}

// float4-vectorized combine
__global__ void k_combine2(const float* __restrict__ pnum, const float* __restrict__ pden,
                           float* __restrict__ fzf) {
    int i4 = blockIdx.x * 256 + threadIdx.x;   // over B*64*NN/4 = 262144
    int b = i4 >> 16, c = (i4 >> 10) & 63, n4 = i4 & 1023;
    float4 num = make_float4(0, 0, 0, 0), den = make_float4(0, 0, 0, 0);
    #pragma unroll
    for (int ch = 0; ch < 4; ch++) {
        float4 pn = ((const float4*)pnum)[((size_t)(b * 4 + ch) * 64 + c) * 1024 + n4];
        float4 pd = ((const float4*)pden)[(size_t)(b * 4 + ch) * 1024 + n4];
        num.x += pn.x; num.y += pn.y; num.z += pn.z; num.w += pn.w;
        den.x += pd.x; den.y += pd.y; den.z += pd.z; den.w += pd.w;
    }
    float4 o = make_float4(num.x / den.x, num.y / den.y, num.z / den.z, num.w / den.w);
    ((float4*)fzf)[((size_t)(b * 64 + c)) * 1024 + n4] = o;
}

// ---------------- 1x1 convs: thread = 4n x 1o, partial stats ----------------
__global__ __launch_bounds__(256) void k_1x1s(const float* __restrict__ in,
                                              const float* __restrict__ wT,
                                              const float* __restrict__ bias,
                                              float* __restrict__ out,
                                              float* __restrict__ pst) {
    int b = blockIdx.z, ob = blockIdx.y, bx = blockIdx.x;
    int tid = threadIdx.x;
    int q = tid & 15, o = ob * 16 + (tid >> 4);
    int n = bx * 64 + q * 4;
    const float* src = in + (size_t)b * 64 * NN + n;
    const float* wp_ = wT + o;
    v4f acc = {0, 0, 0, 0};
    #pragma unroll 8
    for (int c = 0; c < 64; c++) {
        float4 x = *(const float4*)&src[(size_t)c * NN];
        float w = wp_[c * 64];
        acc[0] += x.x * w; acc[1] += x.y * w; acc[2] += x.z * w; acc[3] += x.w * w;
    }
    float bv = bias[o];
    float s = 0, q2 = 0;
    float4 ov;
    float* op = (float*)&ov;
    #pragma unroll
    for (int v = 0; v < 4; v++) {
        float val = acc[v] + bv;
        op[v] = val;
        s += val; q2 += val * val;
    }
    *(float4*)&out[((size_t)(b * 64 + o)) * NN + n] = ov;
    #pragma unroll
    for (int off = 1; off < 16; off <<= 1) {
        s += __shfl_xor(s, off);
        q2 += __shfl_xor(q2, off);
    }
    if (q == 0) {
        int part = bx * 4 + b;
        pst[(o * 256 + part) * 2] = s;
        pst[(o * 256 + part) * 2 + 1] = q2;
    }
}

// fusion: segA=vox, segB=pt(BN+relu on the fly), segC=fzf (pre-combined)
__global__ __launch_bounds__(256) void k_1x1f(const float* __restrict__ vox,
                                              const float* __restrict__ pt,
                                              const float* __restrict__ fzf,
                                              const float* __restrict__ bnB,
                                              const float* __restrict__ wfuT,
                                              const float* __restrict__ bC,
                                              float* __restrict__ out,
                                              float* __restrict__ pst) {
    int b = blockIdx.z, ob = blockIdx.y, bx = blockIdx.x;
    int tid = threadIdx.x;
    int q = tid & 15, o = ob * 16 + (tid >> 4);
    int n = bx * 64 + q * 4;
    const float* srcA = vox + (size_t)b * 64 * NN + n;
    const float* srcB = pt + (size_t)b * 64 * NN + n;
    const float* srcC = fzf + (size_t)b * 64 * NN + n;
    const float* wA = wfuT + o;
    v4f acc = {0, 0, 0, 0};
    #pragma unroll 8
    for (int c = 0; c < 64; c++) {
        float4 x = *(const float4*)&srcA[(size_t)c * NN];
        float w = wA[c * 64];
        acc[0] += x.x * w; acc[1] += x.y * w; acc[2] += x.z * w; acc[3] += x.w * w;
    }
    #pragma unroll 8
    for (int c = 0; c < 64; c++) {
        float4 x = *(const float4*)&srcB[(size_t)c * NN];
        float sc = bnB[2 * c], sh = bnB[2 * c + 1];
        float w = wA[(64 + c) * 64];
        float x0 = fmaxf(x.x * sc + sh, 0.0f), x1 = fmaxf(x.y * sc + sh, 0.0f);
        float x2 = fmaxf(x.z * sc + sh, 0.0f), x3 = fmaxf(x.w * sc + sh, 0.0f);
        acc[0] += x0 * w; acc[1] += x1 * w; acc[2] += x2 * w; acc[3] += x3 * w;
    }
    #pragma unroll 8
    for (int c = 0; c < 64; c++) {
        float4 x = *(const float4*)&srcC[(size_t)c * NN];
        float w = wA[(128 + c) * 64];
        acc[0] += x.x * w; acc[1] += x.y * w; acc[2] += x.z * w; acc[3] += x.w * w;
    }
    float bv = bC[o];
    float s = 0, q2 = 0;
    float4 ov;
    float* op = (float*)&ov;
    #pragma unroll
    for (int v = 0; v < 4; v++) {
        float val = acc[v] + bv;
        op[v] = val;
        s += val; q2 += val * val;
    }
    *(float4*)&out[((size_t)(b * 64 + o)) * NN + n] = ov;
    #pragma unroll
    for (int off = 1; off < 16; off <<= 1) {
        s += __shfl_xor(s, off);
        q2 += __shfl_xor(q2, off);
    }
    if (q == 0) {
        int part = bx * 4 + b;
        pst[(o * 256 + part) * 2] = s;
        pst[(o * 256 + part) * 2 + 1] = q2;
    }
}

// ---------------- launcher ----------------
extern "C" void kernel_launch(void* const* d_in, const int* in_sizes, int n_in,
                              void* d_out, int out_size, void* d_ws, size_t ws_size,
                              hipStream_t stream) {
    const float* features = (const float*)d_in[0];
    const float* coords = (const float*)d_in[1];
    const float* w1 = (const float*)d_in[2];
    const float* g1 = (const float*)d_in[4];
    const float* be1 = (const float*)d_in[5];
    const float* w2 = (const float*)d_in[6];
    const float* g2 = (const float*)d_in[8];
    const float* be2 = (const float*)d_in[9];
    const float* wp = (const float*)d_in[10];
    const float* bp = (const float*)d_in[11];
    const float* gp = (const float*)d_in[12];
    const float* bep = (const float*)d_in[13];
    const float* wf = (const float*)d_in[14];
    const float* bf = (const float*)d_in[15];
    const float* wfu = (const float*)d_in[16];
    const float* bfu = (const float*)d_in[17];
    const float* gfu = (const float*)d_in[18];
    const float* befu = (const float*)d_in[19];

    float* ws = (float*)d_ws;
    float* nc = ws;                        // 49152
    int* vidx = (int*)(ws + 49152);        // 16384 ints
    int* cntI = (int*)(ws + 65536);        // 131072 ints (pden overlays later)
    float* pden = ws + 65536;
    float* gridCL = ws + 196608;           // conv outputs (bf16 raw both convs)
    ushort_t* gTraw = (ushort_t*)gridCL;
    int* rank = (int*)(ws + 196608);       // overlay (pre-conv only)
    int* lscan = (int*)(ws + 327680);
    int* bsum = (int*)(ws + 458752);
    int* bbase = (int*)(ws + 459264);
    int* plist = (int*)(ws + 459776);
    float* featT = ws + 476160;            // 1048576 floats
    float* gTpool = ws + 8585216;          // gT bf16 / pnum / pstB
    ushort_t* gT = (ushort_t*)gTpool;
    float* pnum = gTpool;                  // 4,194,304 floats
    float* pstB = gTpool + 4194304;        // 32768 floats (disjoint from pnum)
    float* stats = ws + 16973824;
    float* voxreg = ws + 16974336;
    ushort_t* wS1 = (ushort_t*)voxreg;
    ushort_t* wS2 = wS1 + 110592;
    float* vox = voxreg;
    float* pt = ws + 18022912;
    float* fzf = ws + 19071488;
    float* wpT = ws + 20120064;
    float* wfuT = wpT + 4096;
    float* bC = wfuT + 12288;
    float* fpre = ws + 21168640;
    ushort_t* featb = (ushort_t*)fpre;
    float* accs = ws + 22217216;

    float* out = (float*)d_out;

    // prep megakernel: fold + accs zero + tws + pfeat + cntI zero
    k_prep<<<1699, 256, 0, stream>>>(wp, wfu, wf, bf, bfu, wpT, wfuT, bC, accs,
                                     w1, w2, wS1, wS2, features, featT, featb, cntI);

    // voxelization: CSR gather-mean (scan1 also zeroes rank)
    k_nc<<<BB, 256, 0, stream>>>(coords, nc, vidx, cntI);
    k_scan1<<<512, 256, 0, stream>>>(cntI, lscan, bsum, rank);
    k_scan2<<<1, 512, 0, stream>>>(bsum, bbase);
    k_fill<<<BB * NN / 256, 256, 0, stream>>>(vidx, lscan, bbase, rank, plist);
    k_gather<<<4096, 256, 0, stream>>>(featT, cntI, lscan, bbase, plist, gT);

    // voxel branch (both convs bf16-out; R19 proven 512-block 8-row tiles)
    k_convlds<1><<<512, 256, 0, stream>>>(gT, wS1, gTraw, accs);
    k_bncast2<<<BB * R3 * 64 / 8 / 256, 256, 0, stream>>>(gTraw, accs, g1, be1,
                                                          1.0f / (BB * R3), 0.1f, gT);
    k_convlds<1><<<512, 256, 0, stream>>>(gT, wS2, gTraw, accs + 128);
    k_devox2<<<dim3(NN / 16, BB), 256, 0, stream>>>(gTraw, accs + 128, g2, be2,
                                                    1.0f / (BB * R3), nc, vox);

    // fuzzy branch
    k_fuzzym<<<dim3(64, 4, BB), 256, 0, stream>>>(coords, featb, pnum, pden);
    k_combine2<<<BB * 64 * NN / 4 / 256, 256, 0, stream>>>(pnum, pden, fzf);

    // point branch
    k_1x1s<<<dim3(NN / 64, 4, BB), 256, 0, stream>>>(features, wpT, bp, pt, pstB);
    k_bnfin2<<<64, 256, 0, stream>>>(pstB, gp, bep, stats + 256, 1.0f / (BB * NN));

    // fusion (BN finalize+apply merged into k_bnact2)
    k_1x1f<<<dim3(NN / 64, 4, BB), 256, 0, stream>>>(vox, pt, fzf, stats + 256, wfuT, bC,
                                                     fpre, pstB);
    k_bnact2<<<BB * 64 * NN / 4 / 256, 256, 0, stream>>>(fpre, pstB, gfu, befu,
                                                         1.0f / (BB * NN), out);

    hipMemcpyAsync(out + (size_t)BB * CO * NN, coords, (size_t)BB * 3 * NN * 4,
                   hipMemcpyDeviceToDevice, stream);
}

// Round 23
// 237.319 us; speedup vs baseline: 1.2264x; 1.0814x over previous
//
#include <hip/hip_runtime.h>
#include <hip/hip_bf16.h>
#include <math.h>

#define RR 32
#define R3 32768
#define BB 4
#define CI 64
#define CO 64
#define NN 4096

typedef short v8s __attribute__((ext_vector_type(8)));
typedef float v4f __attribute__((ext_vector_type(4)));
typedef unsigned short ushort_t;

__device__ __forceinline__ unsigned short f2bf(float f) {
    unsigned int u = __float_as_uint(f);
    unsigned int r = (u + 0x7FFFu + ((u >> 16) & 1u)) >> 16;
    return (unsigned short)r;
}
__device__ __forceinline__ float bf2f(unsigned short h) {
    return __uint_as_float((unsigned int)h << 16);
}

__device__ __forceinline__ void gll16(const void* g, void* l) {
    __builtin_amdgcn_global_load_lds((const __attribute__((address_space(1))) unsigned int*)g,
                                     (__attribute__((address_space(3))) unsigned int*)l, 16, 0, 0);
}

// ---------------- block reduce helpers ----------------
__device__ __forceinline__ float blockReduceSum(float v, float* sm) {
    int tid = threadIdx.x;
    sm[tid] = v; __syncthreads();
    for (int off = 128; off > 0; off >>= 1) {
        if (tid < off) sm[tid] += sm[tid + off];
        __syncthreads();
    }
    float r = sm[0]; __syncthreads();
    return r;
}
__device__ __forceinline__ float blockReduceMax(float v, float* sm) {
    int tid = threadIdx.x;
    sm[tid] = v; __syncthreads();
    for (int off = 128; off > 0; off >>= 1) {
        if (tid < off) sm[tid] = fmaxf(sm[tid], sm[tid + off]);
        __syncthreads();
    }
    float r = sm[0]; __syncthreads();
    return r;
}

// ---------------- prep megakernel: fold + tws + pfeat + cntI zero ----------------
__global__ void k_prep(const float* __restrict__ wp, const float* __restrict__ wfu,
                       const float* __restrict__ wf, const float* __restrict__ bf,
                       const float* __restrict__ bfu,
                       float* __restrict__ wpT, float* __restrict__ wfuT,
                       float* __restrict__ bC, float* __restrict__ accs,
                       const float* __restrict__ w1, const float* __restrict__ w2,
                       ushort_t* __restrict__ wS1, ushort_t* __restrict__ wS2,
                       const float* __restrict__ feat, float* __restrict__ featT,
                       ushort_t* __restrict__ featb, int* __restrict__ cntI) {
    __shared__ float t[64][65];
    int bid = blockIdx.x, tid = threadIdx.x;
    if (bid < 67) {
        int i = bid * 256 + tid;
        if (i < 4096) {
            int c = i >> 6, o = i & 63;
            wpT[c * 64 + o] = wp[o * 64 + c];
        } else if (i < 12288) {
            int j = i - 4096;
            int c = j >> 6, o = j & 63;
            wfuT[c * 64 + o] = wfu[(size_t)o * 192 + c];
        } else if (i < 16384) {
            int j = i - 12288;
            int c = j >> 6, o = j & 63;
            float s = 0;
            for (int k = 0; k < 64; k++)
                s += wfu[(size_t)o * 192 + 128 + k] * wf[(size_t)k * 64 + c];
            wfuT[(128 + c) * 64 + o] = s;
        } else if (i < 16448) {
            int o = i - 16384;
            float s = bfu[o];
            for (int k = 0; k < 64; k++)
                s += wfu[(size_t)o * 192 + 128 + k] * bf[k];
            bC[o] = s;
        } else if (i < 16960) {
            accs[i - 16448] = 0.0f;
        }
    } else if (bid < 931) {
        int i = (bid - 67) * 256 + tid;  // 221184
        const float* w = (i < 110592) ? w1 : w2;
        ushort_t* wS = (i < 110592) ? wS1 : wS2;
        int j = (i < 110592) ? i : i - 110592;
        int cis = j & 31, co = (j >> 5) & 63;
        int dx = (j >> 11) % 3, cih = (j / 6144) & 1, dzdy = j / 12288;
        int k = dzdy * 3 + dx, ci = cih * 32 + cis;
        wS[j] = f2bf(w[((size_t)co * CI + ci) * 27 + k]);
    } else if (bid < 1187) {
        int pb = bid - 931;
        int b = pb >> 6, n0 = (pb & 63) * 64;
        int q = tid >> 6, nl = tid & 63;
        #pragma unroll
        for (int k = 0; k < 16; k++) {
            int c = q * 16 + k;
            float v = feat[((size_t)(b * CI + c)) * NN + n0 + nl];
            t[nl][c] = v;
            featb[((size_t)(b * CI + c)) * NN + n0 + nl] = f2bf(v);
        }
        __syncthreads();
        #pragma unroll
        for (int k = 0; k < 16; k++) {
            int n = q * 16 + k;
            featT[((size_t)b * NN + n0 + n) * 64 + nl] = t[n][nl];
        }
    } else {
        int z = (bid - 1187) * 256 + tid;  // 131072
        cntI[z] = 0;
    }
}

// ---------------- voxel coords + fused voxel count ----------------
__global__ void k_nc(const float* __restrict__ coords, float* __restrict__ nc,
                     int* __restrict__ vidx, int* __restrict__ cntI) {
    int b = blockIdx.x, tid = threadIdx.x;
    __shared__ float sm[256];
    const float* cb = coords + (size_t)b * 3 * NN;
    float s0 = 0, s1 = 0, s2 = 0;
    for (int n = tid; n < NN; n += 256) {
        s0 += cb[n]; s1 += cb[NN + n]; s2 += cb[2 * NN + n];
    }
    float m0 = blockReduceSum(s0, sm) * (1.0f / NN);
    float m1 = blockReduceSum(s1, sm) * (1.0f / NN);
    float m2 = blockReduceSum(s2, sm) * (1.0f / NN);
    float mx = 0;
    for (int n = tid; n < NN; n += 256) {
        float dx = cb[n] - m0, dy = cb[NN + n] - m1, dz = cb[2 * NN + n] - m2;
        mx = fmaxf(mx, dx * dx + dy * dy + dz * dz);
    }
    mx = blockReduceMax(mx, sm);
    float denom = 2.0f * sqrtf(mx);
    float mean[3] = {m0, m1, m2};
    for (int n = tid; n < NN; n += 256) {
        int vi[3];
        #pragma unroll
        for (int ax = 0; ax < 3; ax++) {
            float x = (cb[ax * NN + n] - mean[ax]) / denom + 0.5f;
            x = x * RR;
            x = fminf(fmaxf(x, 0.0f), (float)(RR - 1));
            nc[((size_t)b * 3 + ax) * NN + n] = x;
            vi[ax] = (int)rintf(x);
        }
        int idx = (vi[0] * RR + vi[1]) * RR + vi[2];
        vidx[b * NN + n] = idx;
        atomicAdd(&cntI[b * R3 + idx], 1);
    }
}

// ---------------- scan (also zeroes rank) ----------------
__global__ void k_scan1(const int* __restrict__ cntI, int* __restrict__ lscan,
                        int* __restrict__ bsum, int* __restrict__ rank) {
    __shared__ int sm[256];
    int tid = threadIdx.x;
    int i = blockIdx.x * 256 + tid;
    rank[i] = 0;
    int v = cntI[i];
    sm[tid] = v; __syncthreads();
    for (int off = 1; off < 256; off <<= 1) {
        int t = (tid >= off) ? sm[tid - off] : 0;
        __syncthreads();
        sm[tid] += t;
        __syncthreads();
    }
    lscan[i] = sm[tid] - v;
    if (tid == 255) bsum[blockIdx.x] = sm[tid];
}

__global__ void k_scan2(const int* __restrict__ bsum, int* __restrict__ bbase) {
    __shared__ int sm[512];
    int tid = threadIdx.x;
    int v = bsum[tid];
    sm[tid] = v; __syncthreads();
    for (int off = 1; off < 512; off <<= 1) {
        int t = (tid >= off) ? sm[tid - off] : 0;
        __syncthreads();
        sm[tid] += t;
        __syncthreads();
    }
    bbase[tid] = sm[tid] - v;
}

// ---------------- fill CSR point lists ----------------
__global__ void k_fill(const int* __restrict__ vidx, const int* __restrict__ lscan,
                       const int* __restrict__ bbase, int* __restrict__ rank,
                       int* __restrict__ plist) {
    int i = blockIdx.x * 256 + threadIdx.x;  // B*NN
    int b = i >> 12, n = i & (NN - 1);
    int flat = b * R3 + vidx[i];
    int r = atomicAdd(&rank[flat], 1);
    plist[bbase[flat >> 8] + lscan[flat] + r] = n;
}

// ---------------- segmented gather-mean -> gT bf16 cl ----------------
__global__ __launch_bounds__(256) void k_gather(const float* __restrict__ featT,
                                                const int* __restrict__ cntI,
                                                const int* __restrict__ lscan,
                                                const int* __restrict__ bbase,
                                                const int* __restrict__ plist,
                                                ushort_t* __restrict__ gT) {
    int wv = threadIdx.x >> 6, lane = threadIdx.x & 63;
    int vbase = blockIdx.x * 32 + wv * 8;
    for (int k = 0; k < 8; k++) {
        int flat = vbase + k;
        int count = cntI[flat];
        float s = 0.0f;
        if (count > 0) {
            int b = flat >> 15;
            int start = bbase[flat >> 8] + lscan[flat];
            for (int j = 0; j < count; j++) {
                int n = plist[start + j];
                s += featT[((size_t)b * NN + n) * 64 + lane];
            }
            s *= 1.0f / (float)count;
        }
        gT[(size_t)flat * 64 + lane] = f2bf(s);
    }
}

// ---------------- BN(from accs) + lrelu, bf16 -> bf16 (cl -> cl) ----------------
__global__ void k_bncast2(const ushort_t* __restrict__ x, const float* __restrict__ accs,
                          const float* __restrict__ g, const float* __restrict__ be,
                          float invcnt, float slope, ushort_t* __restrict__ o) {
    size_t i = (size_t)blockIdx.x * 256 + threadIdx.x;  // over B*R3*64/8
    int c0 = (int)((i * 8) & 63);
    float sc[8], sh[8];
    #pragma unroll
    for (int j = 0; j < 8; j++) {
        int c = c0 + j;
        float mean = accs[2 * c] * invcnt;
        float var = accs[2 * c + 1] * invcnt - mean * mean;
        float scale = g[c] * rsqrtf(var + 1e-4f);
        sc[j] = scale;
        sh[j] = be[c] - mean * scale;
    }
    uint4 in = ((const uint4*)x)[i];
    unsigned iv[4] = {in.x, in.y, in.z, in.w};
    unsigned pk[4];
    #pragma unroll
    for (int j = 0; j < 4; j++) {
        float u0 = bf2f((unsigned short)(iv[j] & 0xFFFF)) * sc[2 * j] + sh[2 * j];
        float u1 = bf2f((unsigned short)(iv[j] >> 16)) * sc[2 * j + 1] + sh[2 * j + 1];
        u0 = u0 > 0 ? u0 : slope * u0;
        u1 = u1 > 0 ? u1 : slope * u1;
        pk[j] = (unsigned)f2bf(u0) | ((unsigned)f2bf(u1) << 16);
    }
    ((uint4*)o)[i] = make_uint4(pk[0], pk[1], pk[2], pk[3]);
}

// ---------------- LDS-staged MFMA conv3d 3x3x3 (R19 proven config) ----------------
template <int OUTBF16>
__global__ __launch_bounds__(256) void k_convlds(const ushort_t* __restrict__ gT,
                                                 const ushort_t* __restrict__ wS,
                                                 void* __restrict__ outP,
                                                 float* __restrict__ accs) {
    __shared__ ushort_t lin[20480];     // 40960B input plane (sbuf overlays: 33792B <= 40960B)
    __shared__ ushort_t lw[2][6144];    // 2 x 12288B weights
    int bid = blockIdx.x;
    int wgid = (bid & 7) * 64 + (bid >> 3);
    int yt = wgid & 3, z0 = (wgid >> 2) & 31, b = wgid >> 7;
    int tid = threadIdx.x;
    int w = __builtin_amdgcn_readfirstlane(tid >> 6);
    int lane = tid & 63, l15 = lane & 15, l4 = lane >> 4;
    int y0 = yt * 8;
    const ushort_t* gTb = gT + (size_t)b * R3 * 64;

    int voxF[4];
    #pragma unroll
    for (int f = 0; f < 4; f++)
        voxF[f] = (w * 2 + (f >> 1)) * 32 + (f & 1) * 16 + l15 - 1;
    bool xlo_ok = (l15 != 0), xhi_ok = (l15 != 15);

    int lsw = lane ^ ((lane >> 3) & 7);
    int wsz8 = ((l15 * 4 + l4) ^ ((l15 >> 1) & 7)) * 8;

    const v8s vzero = {};
    v4f acc[4][4];
    #pragma unroll
    for (int m = 0; m < 4; m++)
        #pragma unroll
        for (int f = 0; f < 4; f++)
            acc[m][f] = (v4f){0.0f, 0.0f, 0.0f, 0.0f};

#define WSTAGE(s)                                                              \
    do {                                                                       \
        const ushort_t* _src = wS + (size_t)(s) * 6144;                        \
        ushort_t* _dst = lw[(s) & 1];                                          \
        _Pragma("unroll") for (int _i = 0; _i < 3; _i++) {                     \
            int _pb = _i * 256 + w * 64;                                       \
            gll16(_src + (size_t)(_pb + lsw) * 8, _dst + (size_t)(_pb + lane) * 8); \
        }                                                                      \
    } while (0)

#define ISTAGE(dz)                                                             \
    do {                                                                       \
        int _zp = z0 - 1 + (dz);                                               \
        if (_zp < 0 || _zp > 31) {                                             \
            for (int _q = 0; _q < 10; _q++)                                    \
                *(v8s*)&lin[(size_t)(w * 640 + _q * 64 + lane) * 8] = vzero;   \
        } else {                                                               \
            if (yt == 0) *(v8s*)&lin[(size_t)tid * 8] = vzero;                 \
            if (yt == 3) *(v8s*)&lin[(size_t)(2304 + tid) * 8] = vzero;        \
            const ushort_t* _pb = gTb + ((size_t)_zp * 1024 + (size_t)(y0 - 1) * 32) * 64; \
            int _g0 = (yt == 0) ? 256 : 0;                                     \
            int _nc = 10 - (yt == 0) - (yt == 3);                               \
            for (int _i = 0; _i < _nc; _i++) {                                 \
                int _pbase = _g0 + _i * 256 + w * 64;                          \
                int _p = _pbase + lane;                                        \
                int _vx = _p >> 3, _js = _p & 7;                               \
                int _sg = _vx * 8 + (_js ^ (_vx & 7));                         \
                gll16(_pb + (size_t)_sg * 8, lin + (size_t)_pbase * 8);        \
            }                                                                  \
        }                                                                      \
    } while (0)

    WSTAGE(0);
    for (int s = 0; s < 18; s++) {
        int dy = (s / 2) % 3, cih = s & 1;
        asm volatile("s_barrier" ::: "memory");
        if ((s % 6) == 0) ISTAGE(s / 6);
        if (s + 1 < 18) WSTAGE(s + 1);
        if (s + 1 < 18) asm volatile("s_waitcnt vmcnt(3) lgkmcnt(0)" ::: "memory");
        else            asm volatile("s_waitcnt vmcnt(0) lgkmcnt(0)" ::: "memory");
        asm volatile("s_barrier" ::: "memory");

        const ushort_t* lwb = lw[s & 1];
        #pragma unroll
        for (int dx = 0; dx < 3; dx++) {
            v8s Bf[4];
            #pragma unroll
            for (int f = 0; f < 4; f++) {
                int vox = voxF[f] + dy * 32 + dx;
                int g = vox * 8 + ((cih * 4 + l4) ^ (vox & 7));
                int bix = g * 16;
                bix = bix < 0 ? 0 : bix;
                v8s vb = *(const v8s*)((const char*)lin + bix);
                bool ok = (dx == 0 && (f & 1) == 0) ? xlo_ok :
                          (dx == 2 && (f & 1) == 1) ? xhi_ok : true;
                Bf[f] = ok ? vb : vzero;
            }
            const ushort_t* ap = lwb + dx * 2048 + wsz8;
            #pragma unroll
            for (int m = 0; m < 4; m++) {
                v8s Af = *(const v8s*)(ap + m * 512);
                #pragma unroll
                for (int f = 0; f < 4; f++)
                    acc[m][f] = __builtin_amdgcn_mfma_f32_16x16x32_bf16(Af, Bf[f], acc[m][f], 0, 0, 0);
            }
        }
    }

    // stores
    #pragma unroll
    for (int m = 0; m < 4; m++) {
        #pragma unroll
        for (int f = 0; f < 4; f++) {
            int y = y0 + w * 2 + (f >> 1);
            int x = (f & 1) * 16 + l15;
            size_t base = ((size_t)b * R3 + z0 * 1024 + y * 32 + x) * 64 + m * 16 + l4 * 4;
            if (OUTBF16) {
                unsigned p0 = (unsigned)f2bf(acc[m][f][0]) | ((unsigned)f2bf(acc[m][f][1]) << 16);
                unsigned p1 = (unsigned)f2bf(acc[m][f][2]) | ((unsigned)f2bf(acc[m][f][3]) << 16);
                *(uint2*)&((ushort_t*)outP)[base] = make_uint2(p0, p1);
            } else {
                float4 o = make_float4(acc[m][f][0], acc[m][f][1], acc[m][f][2], acc[m][f][3]);
                *(float4*)&((float*)outP)[base] = o;
            }
        }
    }

    // fused BN-stats (sbuf overlays lin; stride-33: conflict-free)
    __syncthreads();
    float* sbuf = (float*)lin;
    #pragma unroll
    for (int m = 0; m < 4; m++)
        #pragma unroll
        for (int r = 0; r < 4; r++) {
            float s = 0, q = 0;
            #pragma unroll
            for (int f = 0; f < 4; f++) {
                float v = acc[m][f][r];
                s += v; q += v * v;
            }
            sbuf[tid * 33 + (m * 4 + r) * 2] = s;
            sbuf[tid * 33 + (m * 4 + r) * 2 + 1] = q;
        }
    __syncthreads();
    if (tid < 128) {
        int co = tid >> 1, val = tid & 1;
        int m = co >> 4, cl4 = (co >> 2) & 3, r = co & 3;
        float a = 0;
        for (int w2 = 0; w2 < 4; w2++)
            for (int l = 0; l < 16; l++)
                a += sbuf[(w2 * 64 + cl4 * 16 + l) * 33 + (m * 4 + r) * 2 + val];
        atomicAdd(&accs[2 * co + val], a);
    }
#undef WSTAGE
#undef ISTAGE
}

// ---------------- mid megakernel: devox2 | fuzzym | 1x1s ----------------
// blocks [0,1024): devoxelize+BN ; [1024,2048): fuzzy attention ; [2048,3072): point 1x1
__global__ __launch_bounds__(256) void k_mid(
        const ushort_t* __restrict__ gcl, const float* __restrict__ accs2,
        const float* __restrict__ g2, const float* __restrict__ be2, float invcntR3,
        const float* __restrict__ nc, float* __restrict__ vox,
        const float* __restrict__ coords, const ushort_t* __restrict__ featb,
        float* __restrict__ pnum, float* __restrict__ pden,
        const float* __restrict__ features, const float* __restrict__ wpT,
        const float* __restrict__ bp, float* __restrict__ pt, float* __restrict__ pstB) {
    __shared__ float cm[3][1024];
    __shared__ ushort_t la[4][2048];
    int bid0 = blockIdx.x, tid = threadIdx.x;

    if (bid0 < 1024) {
        // ---- devox2 ----
        int b = bid0 >> 8;
        int nblk = bid0 & 255;
        int p = tid >> 4, q = tid & 15;
        int n = nblk * 16 + p;
        float x = nc[((size_t)b * 3 + 0) * NN + n];
        float y = nc[((size_t)b * 3 + 1) * NN + n];
        float z = nc[((size_t)b * 3 + 2) * NN + n];
        float fx = floorf(x), fy = floorf(y), fz = floorf(z);
        int lx = (int)fx, ly = (int)fy, lz = (int)fz;
        int hx = min(lx + 1, RR - 1), hy = min(ly + 1, RR - 1), hz = min(lz + 1, RR - 1);
        float frx = x - fx, fry = y - fy, frz = z - fz;
        int xx[2] = {lx, hx}, yy[2] = {ly, hy}, zz[2] = {lz, hz};
        float wx[2] = {1.0f - frx, frx}, wy[2] = {1.0f - fry, fry}, wz[2] = {1.0f - frz, frz};
        float sc[4], sh[4];
        #pragma unroll
        for (int j = 0; j < 4; j++) {
            int c = q * 4 + j;
            float mean = accs2[2 * c] * invcntR3;
            float var = accs2[2 * c + 1] * invcntR3 - mean * mean;
            float scale = g2[c] * rsqrtf(var + 1e-4f);
            sc[j] = scale;
            sh[j] = be2[c] - mean * scale;
        }
        float a0 = 0, a1 = 0, a2 = 0, a3 = 0;
        #pragma unroll
        for (int dx = 0; dx < 2; dx++)
            #pragma unroll
            for (int dy = 0; dy < 2; dy++)
                #pragma unroll
                for (int dz = 0; dz < 2; dz++) {
                    int idx = (xx[dx] * RR + yy[dy]) * RR + zz[dz];
                    float wt = wx[dx] * wy[dy] * wz[dz];
                    uint2 pv = *(const uint2*)&gcl[((size_t)b * R3 + idx) * 64 + q * 4];
                    float v0 = bf2f((unsigned short)(pv.x & 0xFFFF));
                    float v1 = bf2f((unsigned short)(pv.x >> 16));
                    float v2 = bf2f((unsigned short)(pv.y & 0xFFFF));
                    float v3 = bf2f((unsigned short)(pv.y >> 16));
                    float u0 = v0 * sc[0] + sh[0]; u0 = u0 > 0 ? u0 : 0.1f * u0;
                    float u1 = v1 * sc[1] + sh[1]; u1 = u1 > 0 ? u1 : 0.1f * u1;
                    float u2 = v2 * sc[2] + sh[2]; u2 = u2 > 0 ? u2 : 0.1f * u2;
                    float u3 = v3 * sc[3] + sh[3]; u3 = u3 > 0 ? u3 : 0.1f * u3;
                    a0 += wt * u0; a1 += wt * u1; a2 += wt * u2; a3 += wt * u3;
                }
        vox[((size_t)(b * 64 + q * 4 + 0)) * NN + n] = a0;
        vox[((size_t)(b * 64 + q * 4 + 1)) * NN + n] = a1;
        vox[((size_t)(b * 64 + q * 4 + 2)) * NN + n] = a2;
        vox[((size_t)(b * 64 + q * 4 + 3)) * NN + n] = a3;
    } else if (bid0 < 2048) {
        // ---- fuzzym ----
        int pb = bid0 - 1024;
        int nt = pb & 63, mc = (pb >> 6) & 3, b = pb >> 8;
        int w = tid >> 6, lane = tid & 63, l15 = lane & 15, l4 = lane >> 4;
        int m0 = mc * 1024;

        for (int i = tid; i < 1024; i += 256) {
            float a0 = coords[((size_t)b * 3 + 0) * NN + m0 + i];
            float a1 = coords[((size_t)b * 3 + 1) * NN + m0 + i];
            float a2 = coords[((size_t)b * 3 + 2) * NN + m0 + i];
            float inv = 1.0f / fmaxf(sqrtf(a0 * a0 + a1 * a1 + a2 * a2), 1e-12f);
            cm[0][i] = a0 * inv; cm[1][i] = a1 * inv; cm[2][i] = a2 * inv;
        }

        int n = nt * 64 + w * 16 + l15;
        float q0 = coords[((size_t)b * 3 + 0) * NN + n];
        float q1 = coords[((size_t)b * 3 + 1) * NN + n];
        float q2 = coords[((size_t)b * 3 + 2) * NN + n];
        float qi = 10.0f / fmaxf(sqrtf(q0 * q0 + q1 * q1 + q2 * q2), 1e-12f);
        q0 *= qi; q1 *= qi; q2 *= qi;

        int srow = tid >> 2, sslot = tid & 3;
        int g0 = sslot ^ ((srow >> 1) & 3);
        const ushort_t* fb = featb + (size_t)b * 64 * NN + m0;
        const ushort_t* sbase = fb + (size_t)srow * NN + g0 * 8;
        int rsw = (l15 >> 1) & 3;

        v4f acc[4];
        #pragma unroll
        for (int cb = 0; cb < 4; cb++) acc[cb] = (v4f){0.0f, 0.0f, 0.0f, 0.0f};
        float den = 0.0f;

        gll16(sbase, &la[0][(size_t)tid * 8]);
        gll16(sbase + 32, &la[1][(size_t)tid * 8]);
        gll16(sbase + 64, &la[2][(size_t)tid * 8]);

        for (int t = 0; t < 32; t++) {
            int cur = t & 3;
            asm volatile("s_waitcnt vmcnt(2)" ::: "memory");
            __syncthreads();
            if (t + 3 < 32)
                gll16(sbase + (t + 3) * 32, &la[(t + 3) & 3][(size_t)tid * 8]);

            int mo = t * 32 + l4 * 8;
            float e[8];
            #pragma unroll
            for (int jj = 0; jj < 2; jj++) {
                float4 x0 = *(const float4*)&cm[0][mo + jj * 4];
                float4 x1 = *(const float4*)&cm[1][mo + jj * 4];
                float4 x2 = *(const float4*)&cm[2][mo + jj * 4];
                e[jj * 4 + 0] = __expf(q0 * x0.x + q1 * x1.x + q2 * x2.x);
                e[jj * 4 + 1] = __expf(q0 * x0.y + q1 * x1.y + q2 * x2.y);
                e[jj * 4 + 2] = __expf(q0 * x0.z + q1 * x1.z + q2 * x2.z);
                e[jj * 4 + 3] = __expf(q0 * x0.w + q1 * x1.w + q2 * x2.w);
            }
            den += ((e[0] + e[1]) + (e[2] + e[3])) + ((e[4] + e[5]) + (e[6] + e[7]));
            union { __hip_bfloat162 h[4]; v8s v; } pk;
            pk.h[0] = __float22bfloat162_rn(make_float2(e[0], e[1]));
            pk.h[1] = __float22bfloat162_rn(make_float2(e[2], e[3]));
            pk.h[2] = __float22bfloat162_rn(make_float2(e[4], e[5]));
            pk.h[3] = __float22bfloat162_rn(make_float2(e[6], e[7]));
            #pragma unroll
            for (int cb = 0; cb < 4; cb++) {
                v8s A = *(const v8s*)&la[cur][(size_t)((cb * 16 + l15) * 4 + (l4 ^ rsw)) * 8];
                acc[cb] = __builtin_amdgcn_mfma_f32_16x16x32_bf16(A, pk.v, acc[cb], 0, 0, 0);
            }
        }

        den += __shfl_xor(den, 16);
        den += __shfl_xor(den, 32);

        size_t obase = ((size_t)(b * 4 + mc)) * 64 * NN;
        #pragma unroll
        for (int cb = 0; cb < 4; cb++)
            #pragma unroll
            for (int r = 0; r < 4; r++)
                pnum[obase + (size_t)(cb * 16 + l4 * 4 + r) * NN + n] = acc[cb][r];
        if (l4 == 0) pden[((size_t)(b * 4 + mc)) * NN + n] = den;
    } else {
        // ---- 1x1s (point branch) ----
        int pb = bid0 - 2048;
        int bx = pb & 63, ob = (pb >> 6) & 3, b = pb >> 8;
        int q = tid & 15, o = ob * 16 + (tid >> 4);
        int n = bx * 64 + q * 4;
        const float* src = features + (size_t)b * 64 * NN + n;
        const float* wp_ = wpT + o;
        v4f acc = {0, 0, 0, 0};
        #pragma unroll 8
        for (int c = 0; c < 64; c++) {
            float4 x = *(const float4*)&src[(size_t)c * NN];
            float w = wp_[c * 64];
            acc[0] += x.x * w; acc[1] += x.y * w; acc[2] += x.z * w; acc[3] += x.w * w;
        }
        float bv = bp[o];
        float s = 0, q2 = 0;
        float4 ov;
        float* op = (float*)&ov;
        #pragma unroll
        for (int v = 0; v < 4; v++) {
            float val = acc[v] + bv;
            op[v] = val;
            s += val; q2 += val * val;
        }
        *(float4*)&pt[((size_t)(b * 64 + o)) * NN + n] = ov;
        #pragma unroll
        for (int off = 1; off < 16; off <<= 1) {
            s += __shfl_xor(s, off);
            q2 += __shfl_xor(q2, off);
        }
        if (q == 0) {
            int part = bx * 4 + b;
            pstB[(o * 256 + part) * 2] = s;
            pstB[(o * 256 + part) * 2 + 1] = q2;
        }
    }
}

// ---------------- fin megakernel: combine2 | bnfin2 ----------------
// blocks [0,1024): combine (f4); [1024,1088): pt BN finalize
__global__ void k_fin(const float* __restrict__ pnum, const float* __restrict__ pden,
                      float* __restrict__ fzf,
                      const float* __restrict__ pst, const float* __restrict__ g,
                      const float* __restrict__ be, float* __restrict__ stats,
                      float invcnt) {
    __shared__ float rs[256], rq[256];
    int bid = blockIdx.x, tid = threadIdx.x;
    if (bid < 1024) {
        int i4 = bid * 256 + tid;
        int b = i4 >> 16, c = (i4 >> 10) & 63, n4 = i4 & 1023;
        float4 num = make_float4(0, 0, 0, 0), den = make_float4(0, 0, 0, 0);
        #pragma unroll
        for (int ch = 0; ch < 4; ch++) {
            float4 pn = ((const float4*)pnum)[((size_t)(b * 4 + ch) * 64 + c) * 1024 + n4];
            float4 pd = ((const float4*)pden)[(size_t)(b * 4 + ch) * 1024 + n4];
            num.x += pn.x; num.y += pn.y; num.z += pn.z; num.w += pn.w;
            den.x += pd.x; den.y += pd.y; den.z += pd.z; den.w += pd.w;
        }
        float4 o = make_float4(num.x / den.x, num.y / den.y, num.z / den.z, num.w / den.w);
        ((float4*)fzf)[((size_t)(b * 64 + c)) * 1024 + n4] = o;
    } else {
        int c = bid - 1024;
        rs[tid] = pst[(c * 256 + tid) * 2];
        rq[tid] = pst[(c * 256 + tid) * 2 + 1];
        __syncthreads();
        for (int off = 128; off > 0; off >>= 1) {
            if (tid < off) { rs[tid] += rs[tid + off]; rq[tid] += rq[tid + off]; }
            __syncthreads();
        }
        if (tid == 0) {
            float mean = rs[0] * invcnt;
            float var = rq[0] * invcnt - mean * mean;
            float sc = g[c] * rsqrtf(var + 1e-4f);
            stats[2 * c] = sc;
            stats[2 * c + 1] = be[c] - mean * sc;
        }
    }
}

// fusion: segA=vox, segB=pt(BN+relu on the fly), segC=fzf (pre-combined)
__global__ __launch_bounds__(256) void k_1x1f(const float* __restrict__ vox,
                                              const float* __restrict__ pt,
                                              const float* __restrict__ fzf,
                                              const float* __restrict__ bnB,
                                              const float* __restrict__ wfuT,
                                              const float* __restrict__ bC,
                                              float* __restrict__ out,
                                              float* __restrict__ pst) {
    int b = blockIdx.z, ob = blockIdx.y, bx = blockIdx.x;
    int tid = threadIdx.x;
    int q = tid & 15, o = ob * 16 + (tid >> 4);
    int n = bx * 64 + q * 4;
    const float* srcA = vox + (size_t)b * 64 * NN + n;
    const float* srcB = pt + (size_t)b * 64 * NN + n;
    const float* srcC = fzf + (size_t)b * 64 * NN + n;
    const float* wA = wfuT + o;
    v4f acc = {0, 0, 0, 0};
    #pragma unroll 8
    for (int c = 0; c < 64; c++) {
        float4 x = *(const float4*)&srcA[(size_t)c * NN];
        float w = wA[c * 64];
        acc[0] += x.x * w; acc[1] += x.y * w; acc[2] += x.z * w; acc[3] += x.w * w;
    }
    #pragma unroll 8
    for (int c = 0; c < 64; c++) {
        float4 x = *(const float4*)&srcB[(size_t)c * NN];
        float sc = bnB[2 * c], sh = bnB[2 * c + 1];
        float w = wA[(64 + c) * 64];
        float x0 = fmaxf(x.x * sc + sh, 0.0f), x1 = fmaxf(x.y * sc + sh, 0.0f);
        float x2 = fmaxf(x.z * sc + sh, 0.0f), x3 = fmaxf(x.w * sc + sh, 0.0f);
        acc[0] += x0 * w; acc[1] += x1 * w; acc[2] += x2 * w; acc[3] += x3 * w;
    }
    #pragma unroll 8
    for (int c = 0; c < 64; c++) {
        float4 x = *(const float4*)&srcC[(size_t)c * NN];
        float w = wA[(128 + c) * 64];
        acc[0] += x.x * w; acc[1] += x.y * w; acc[2] += x.z * w; acc[3] += x.w * w;
    }
    float bv = bC[o];
    float s = 0, q2 = 0;
    float4 ov;
    float* op = (float*)&ov;
    #pragma unroll
    for (int v = 0; v < 4; v++) {
        float val = acc[v] + bv;
        op[v] = val;
        s += val; q2 += val * val;
    }
    *(float4*)&out[((size_t)(b * 64 + o)) * NN + n] = ov;
    #pragma unroll
    for (int off = 1; off < 16; off <<= 1) {
        s += __shfl_xor(s, off);
        q2 += __shfl_xor(q2, off);
    }
    if (q == 0) {
        int part = bx * 4 + b;
        pst[(o * 256 + part) * 2] = s;
        pst[(o * 256 + part) * 2 + 1] = q2;
    }
}

// ---------------- fused BN finalize+apply + coords tail copy ----------------
// blocks [0,1024): BN apply; [1024,1072): coords copy (f4)
__global__ void k_bnact2(const float* __restrict__ x, const float* __restrict__ pst,
                         const float* __restrict__ g, const float* __restrict__ be,
                         float invcnt, float* __restrict__ out,
                         const float* __restrict__ coords, float* __restrict__ outc) {
    int bid = blockIdx.x, tid = threadIdx.x;
    if (bid >= 1024) {
        int i4 = (bid - 1024) * 256 + tid;   // 12288 f4 = 49152 floats
        ((float4*)outc)[i4] = ((const float4*)coords)[i4];
        return;
    }
    int c = (bid >> 2) & 63;
    __shared__ float rs[256], rq[256];
    __shared__ float sscale, sshift;
    rs[tid] = pst[(c * 256 + tid) * 2];
    rq[tid] = pst[(c * 256 + tid) * 2 + 1];
    __syncthreads();
    for (int off = 128; off > 0; off >>= 1) {
        if (tid < off) { rs[tid] += rs[tid + off]; rq[tid] += rq[tid + off]; }
        __syncthreads();
    }
    if (tid == 0) {
        float mean = rs[0] * invcnt;
        float var = rq[0] * invcnt - mean * mean;
        float sc = g[c] * rsqrtf(var + 1e-4f);
        sscale = sc;
        sshift = be[c] - mean * sc;
    }
    __syncthreads();
    float sc = sscale, sh = sshift;
    size_t i = (size_t)bid * 256 + tid;
    float4 v = ((const float4*)x)[i];
    v.x = fmaxf(v.x * sc + sh, 0.0f);
    v.y = fmaxf(v.y * sc + sh, 0.0f);
    v.z = fmaxf(v.z * sc + sh, 0.0f);
    v.w = fmaxf(v.w * sc + sh, 0.0f);
    ((float4*)out)[i] = v;
}

// ---------------- launcher ----------------
extern "C" void kernel_launch(void* const* d_in, const int* in_sizes, int n_in,
                              void* d_out, int out_size, void* d_ws, size_t ws_size,
                              hipStream_t stream) {
    const float* features = (const float*)d_in[0];
    const float* coords = (const float*)d_in[1];
    const float* w1 = (const float*)d_in[2];
    const float* g1 = (const float*)d_in[4];
    const float* be1 = (const float*)d_in[5];
    const float* w2 = (const float*)d_in[6];
    const float* g2 = (const float*)d_in[8];
    const float* be2 = (const float*)d_in[9];
    const float* wp = (const float*)d_in[10];
    const float* bp = (const float*)d_in[11];
    const float* gp = (const float*)d_in[12];
    const float* bep = (const float*)d_in[13];
    const float* wf = (const float*)d_in[14];
    const float* bf = (const float*)d_in[15];
    const float* wfu = (const float*)d_in[16];
    const float* bfu = (const float*)d_in[17];
    const float* gfu = (const float*)d_in[18];
    const float* befu = (const float*)d_in[19];

    float* ws = (float*)d_ws;
    float* nc = ws;                        // 49152
    int* vidx = (int*)(ws + 49152);        // 16384 ints
    int* cntI = (int*)(ws + 65536);        // 131072 ints (pden overlays later)
    float* pden = ws + 65536;
    float* gridCL = ws + 196608;           // conv outputs (bf16 raw both convs)
    ushort_t* gTraw = (ushort_t*)gridCL;
    int* rank = (int*)(ws + 196608);       // overlay (pre-conv only)
    int* lscan = (int*)(ws + 327680);
    int* bsum = (int*)(ws + 458752);
    int* bbase = (int*)(ws + 459264);
    int* plist = (int*)(ws + 459776);
    float* featT = ws + 476160;            // 1048576 floats
    float* gTpool = ws + 8585216;          // gT bf16 / pnum / pstB
    ushort_t* gT = (ushort_t*)gTpool;
    float* pnum = gTpool;                  // 4,194,304 floats
    float* pstB = gTpool + 4194304;        // 32768 floats (disjoint from pnum)
    float* stats = ws + 16973824;
    float* voxreg = ws + 16974336;
    ushort_t* wS1 = (ushort_t*)voxreg;
    ushort_t* wS2 = wS1 + 110592;
    float* vox = voxreg;
    float* pt = ws + 18022912;
    float* fzf = ws + 19071488;
    float* wpT = ws + 20120064;
    float* wfuT = wpT + 4096;
    float* bC = wfuT + 12288;
    float* fpre = ws + 21168640;
    ushort_t* featb = (ushort_t*)fpre;
    float* accs = ws + 22217216;

    float* out = (float*)d_out;

    // prep megakernel: fold + accs zero + tws + pfeat + cntI zero
    k_prep<<<1699, 256, 0, stream>>>(wp, wfu, wf, bf, bfu, wpT, wfuT, bC, accs,
                                     w1, w2, wS1, wS2, features, featT, featb, cntI);

    // voxelization: CSR gather-mean (scan1 also zeroes rank)
    k_nc<<<BB, 256, 0, stream>>>(coords, nc, vidx, cntI);
    k_scan1<<<512, 256, 0, stream>>>(cntI, lscan, bsum, rank);
    k_scan2<<<1, 512, 0, stream>>>(bsum, bbase);
    k_fill<<<BB * NN / 256, 256, 0, stream>>>(vidx, lscan, bbase, rank, plist);
    k_gather<<<4096, 256, 0, stream>>>(featT, cntI, lscan, bbase, plist, gT);

    // voxel branch (both convs bf16-out; R19 proven 512-block 8-row tiles)
    k_convlds<1><<<512, 256, 0, stream>>>(gT, wS1, gTraw, accs);
    k_bncast2<<<BB * R3 * 64 / 8 / 256, 256, 0, stream>>>(gTraw, accs, g1, be1,
                                                          1.0f / (BB * R3), 0.1f, gT);
    k_convlds<1><<<512, 256, 0, stream>>>(gT, wS2, gTraw, accs + 128);

    // mid megakernel: devox2 | fuzzym | 1x1s
    k_mid<<<3072, 256, 0, stream>>>(gTraw, accs + 128, g2, be2, 1.0f / (BB * R3), nc, vox,
                                    coords, featb, pnum, pden,
                                    features, wpT, bp, pt, pstB);

    // fin megakernel: combine2 | pt BN finalize
    k_fin<<<1088, 256, 0, stream>>>(pnum, pden, fzf, pstB, gp, bep, stats + 256,
                                    1.0f / (BB * NN));

    // fusion
    k_1x1f<<<dim3(NN / 64, 4, BB), 256, 0, stream>>>(vox, pt, fzf, stats + 256, wfuT, bC,
                                                     fpre, pstB);
    // BN finalize+apply + coords tail copy
    k_bnact2<<<1072, 256, 0, stream>>>(fpre, pstB, gfu, befu, 1.0f / (BB * NN), out,
                                       coords, out + (size_t)BB * CO * NN);
}